// Round 3
// baseline (21779.059 us; speedup 1.0000x reference)
//
#include <hip/hip_runtime.h>

#define N_NODES 1000000
#define N_EDGES 4000000
#define N_GRAPHS 32768
#define BN_EPS 1e-5f

// ---------------------------------------------------------------------------
// Scratch lives in static device globals, NOT d_ws: the pipeline inherently
// needs ~1 GB of intermediates (1M x 128 f32 x 2) and ws_size appears to be
// smaller (rounds 1-2 faulted with a ws-based layout). Loader-allocated BSS
// is graph-capture safe and never poisoned by the harness. Every element read
// is written earlier in the SAME kernel_launch call (no cross-call state).
// ---------------------------------------------------------------------------
__device__ float g_h[128000000];     // 512 MB: node features (q / h)
__device__ float g_agg[128000000];   // 512 MB: aggregation buffer (+ pool/head scratch)
__device__ float g_dinv[1000000];    //   4 MB: deg^{-1/2}

// ---------------- gcn norm ----------------

__global__ __launch_bounds__(256) void k_fill1(int n) {
    int i = blockIdx.x * 256 + threadIdx.x;
    if (i < n) g_dinv[i] = 1.0f;            // deg starts at 1 (self-loop)
}

__global__ __launch_bounds__(256) void k_edge_deg(const int* __restrict__ dst) {
    int e = blockIdx.x * 256 + threadIdx.x;
    if (e < N_EDGES) atomicAdd(&g_dinv[dst[e]], 1.0f);
}

__global__ __launch_bounds__(256) void k_rsqrt_inplace(int n) {
    int i = blockIdx.x * 256 + threadIdx.x;
    if (i < n) g_dinv[i] = rsqrtf(g_dinv[i]);   // deg >= 1 always
}

// ---------------- layer 1: aggregate 7-dim input, then 7->128 linear --------
// p7[i] = dinv[i]*x[i]; agg7 initialized to p7 (the self-loop term).
// agg7 = g_agg[0 .. 7M), p7 = g_agg[7M .. 14M)

__global__ __launch_bounds__(256) void k_p7(const float* __restrict__ x) {
    int i = blockIdx.x * 256 + threadIdx.x;
    if (i >= N_NODES) return;
    float w = g_dinv[i];
    float* agg7 = g_agg;
    float* p7   = g_agg + 7000000;
#pragma unroll
    for (int k = 0; k < 7; ++k) {
        float v = x[i * 7 + k] * w;
        p7[i * 7 + k] = v;
        agg7[i * 7 + k] = v;
    }
}

__global__ __launch_bounds__(256) void k_edge_agg7(const int* __restrict__ src,
                                                   const int* __restrict__ dst) {
    int e = blockIdx.x * 256 + threadIdx.x;
    if (e >= N_EDGES) return;
    int s = src[e], d = dst[e];
    float* agg7 = g_agg;
    const float* p7 = g_agg + 7000000;
#pragma unroll
    for (int k = 0; k < 7; ++k) atomicAdd(&agg7[d * 7 + k], p7[s * 7 + k]);
}

// z = agg7 . W1 ; (A_hat X W1)[d] = dinv[d]*z ; h1 = relu(bn(z' + b));
// store q1 = dinv*h1 into g_h (premultiplied storage).
__global__ __launch_bounds__(256) void k_lin1_bn_relu(const float* __restrict__ W,
                                                      const float* __restrict__ b,
                                                      const float* __restrict__ g,
                                                      const float* __restrict__ bt,
                                                      const float* __restrict__ rm,
                                                      const float* __restrict__ rv) {
    int t = blockIdx.x * 256 + threadIdx.x;   // node*128 + c
    int i = t >> 7, c = t & 127;
    if (i >= N_NODES) return;
    const float* agg7 = g_agg;
    float z = 0.f;
#pragma unroll
    for (int k = 0; k < 7; ++k) z = fmaf(agg7[i * 7 + k], W[k * 128 + c], z);
    float dv = g_dinv[i];
    z *= dv;
    float sc  = g[c] * rsqrtf(rv[c] + BN_EPS);
    float off = fmaf(b[c] - rm[c], sc, bt[c]);
    g_h[(size_t)i * 128 + c] = fmaxf(fmaf(z, sc, off), 0.f) * dv;
}

// ---------------- 128-dim aggregation (layers 2,3) ----------------

// agg[i] = q[i]  (self-loop term; also overwrites whatever was in g_agg)
__global__ __launch_bounds__(256) void k_selfcopy() {
    int t = blockIdx.x * 256 + threadIdx.x;   // node*32 + chunk4
    int i = t >> 5;
    if (i >= N_NODES) return;
    int c = (t & 31) << 2;
    *(float4*)(g_agg + (size_t)i * 128 + c) = *(const float4*)(g_h + (size_t)i * 128 + c);
}

__global__ __launch_bounds__(256) void k_edge_agg(const int* __restrict__ src,
                                                  const int* __restrict__ dst) {
    int t = blockIdx.x * 256 + threadIdx.x;   // edge*32 + chunk4
    int e = t >> 5;
    if (e >= N_EDGES) return;
    int c = (t & 31) << 2;
    int s = src[e], d = dst[e];
    float4 v = *(const float4*)(g_h + (size_t)s * 128 + c);
    float* o = g_agg + (size_t)d * 128 + c;
    atomicAdd(o + 0, v.x);
    atomicAdd(o + 1, v.y);
    atomicAdd(o + 2, v.z);
    atomicAdd(o + 3, v.w);
}

// ---------------- fused 128x128 GEMM + dinv + bias + BN + ReLU --------------
// tile: 64 rows x 128 cols per block of 256 threads; TM=4, TN=8
// LDS: As 64x132 (pad) = 33.8 KB + Ws 32x128 = 16.4 KB -> ~50 KB
// PRE: multiply output by dinv[row] again (premultiplied storage for next agg)

template <bool PRE>
__global__ __launch_bounds__(256) void k_gemm_bn_relu(const float* __restrict__ W,
                                                      const float* __restrict__ b,
                                                      const float* __restrict__ g,
                                                      const float* __restrict__ bt,
                                                      const float* __restrict__ rm,
                                                      const float* __restrict__ rv) {
    __shared__ float As[64][132];
    __shared__ float Ws[32][128];
    const int tid = threadIdx.x;
    const size_t row0 = (size_t)blockIdx.x * 64;

#pragma unroll
    for (int i = 0; i < 8; ++i) {
        int t = tid + i * 256;
        int r = t >> 5, k4 = (t & 31) << 2;
        *(float4*)(&As[r][k4]) = *(const float4*)(g_agg + (row0 + r) * 128 + k4);
    }

    float acc[4][8];
#pragma unroll
    for (int r = 0; r < 4; ++r)
#pragma unroll
        for (int j = 0; j < 8; ++j) acc[r][j] = 0.f;

    const int tr = tid >> 4;   // 0..15 -> rows tr*4 .. tr*4+3
    const int tc = tid & 15;   // 0..15 -> cols tc*4..+3 and 64+tc*4..+3

    for (int kb = 0; kb < 4; ++kb) {
        __syncthreads();
#pragma unroll
        for (int i = 0; i < 4; ++i) {
            int t = tid + i * 256;
            int r = t >> 5, k4 = (t & 31) << 2;
            *(float4*)(&Ws[r][k4]) = *(const float4*)(W + (size_t)(kb * 32 + r) * 128 + k4);
        }
        __syncthreads();
#pragma unroll
        for (int k = 0; k < 32; ++k) {
            float a[4];
#pragma unroll
            for (int r = 0; r < 4; ++r) a[r] = As[tr * 4 + r][kb * 32 + k];
            float4 w0 = *(const float4*)(&Ws[k][tc * 4]);
            float4 w1 = *(const float4*)(&Ws[k][64 + tc * 4]);
            float w[8] = {w0.x, w0.y, w0.z, w0.w, w1.x, w1.y, w1.z, w1.w};
#pragma unroll
            for (int r = 0; r < 4; ++r)
#pragma unroll
                for (int j = 0; j < 8; ++j)
                    acc[r][j] = fmaf(a[r], w[j], acc[r][j]);
        }
    }

    float4 dv4 = *(const float4*)(g_dinv + row0 + tr * 4);
    float dv[4] = {dv4.x, dv4.y, dv4.z, dv4.w};

#pragma unroll
    for (int half = 0; half < 2; ++half) {
        int cb = half * 64 + tc * 4;
        float s0 = g[cb + 0] * rsqrtf(rv[cb + 0] + BN_EPS);
        float s1 = g[cb + 1] * rsqrtf(rv[cb + 1] + BN_EPS);
        float s2 = g[cb + 2] * rsqrtf(rv[cb + 2] + BN_EPS);
        float s3 = g[cb + 3] * rsqrtf(rv[cb + 3] + BN_EPS);
        float o0 = fmaf(b[cb + 0] - rm[cb + 0], s0, bt[cb + 0]);
        float o1 = fmaf(b[cb + 1] - rm[cb + 1], s1, bt[cb + 1]);
        float o2 = fmaf(b[cb + 2] - rm[cb + 2], s2, bt[cb + 2]);
        float o3 = fmaf(b[cb + 3] - rm[cb + 3], s3, bt[cb + 3]);
#pragma unroll
        for (int r = 0; r < 4; ++r) {
            float pm = PRE ? dv[r] : 1.0f;
            float4 o;
            o.x = fmaxf(fmaf(acc[r][half * 4 + 0] * dv[r], s0, o0), 0.f) * pm;
            o.y = fmaxf(fmaf(acc[r][half * 4 + 1] * dv[r], s1, o1), 0.f) * pm;
            o.z = fmaxf(fmaf(acc[r][half * 4 + 2] * dv[r], s2, o2), 0.f) * pm;
            o.w = fmaxf(fmaf(acc[r][half * 4 + 3] * dv[r], s3, o3), 0.f) * pm;
            *(float4*)(g_h + (row0 + tr * 4 + r) * 128 + cb) = o;
        }
    }
}

// ---------------- pooling + head (scratch reuses g_agg, now dead) -----------
// pooled = g_agg[0 .. 4.19M), cnt = next 32768, hidden = next 2.1M

__global__ __launch_bounds__(256) void k_zero_pool() {
    int i = blockIdx.x * 256 + threadIdx.x;
    if (i < N_GRAPHS * 129) g_agg[i] = 0.0f;   // covers pooled + cnt
}

__global__ __launch_bounds__(256) void k_pool(const int* __restrict__ batch) {
    int t = blockIdx.x * 256 + threadIdx.x;  // node*32 + chunk4
    int i = t >> 5;
    if (i >= N_NODES) return;
    int c = (t & 31) << 2;
    int grp = batch[i];
    float4 v = *(const float4*)(g_h + (size_t)i * 128 + c);
    float* o = g_agg + (size_t)grp * 128 + c;
    atomicAdd(o + 0, v.x);
    atomicAdd(o + 1, v.y);
    atomicAdd(o + 2, v.z);
    atomicAdd(o + 3, v.w);
}

__global__ __launch_bounds__(256) void k_cnt(const int* __restrict__ batch) {
    int i = blockIdx.x * 256 + threadIdx.x;
    if (i < N_NODES) atomicAdd(&g_agg[(size_t)N_GRAPHS * 128 + batch[i]], 1.0f);
}

__global__ __launch_bounds__(256) void k_head1(const float* __restrict__ Wc1,
                                               const float* __restrict__ bc1) {
    int t = blockIdx.x * 256 + threadIdx.x;  // g*64 + c
    int gi = t >> 6, c = t & 63;
    if (gi >= N_GRAPHS) return;
    const float* pooled = g_agg;
    const float* cnt    = g_agg + (size_t)N_GRAPHS * 128;
    float* hidden       = g_agg + (size_t)N_GRAPHS * 128 + N_GRAPHS;
    float inv = 1.0f / fmaxf(cnt[gi], 1.0f);
    float z = 0.f;
#pragma unroll 8
    for (int k = 0; k < 128; ++k) z = fmaf(pooled[gi * 128 + k], Wc1[k * 64 + c], z);
    hidden[t] = fmaxf(fmaf(z, inv, bc1[c]), 0.f);
}

__global__ __launch_bounds__(256) void k_head2(const float* __restrict__ Wc2,
                                               const float* __restrict__ bc2,
                                               float* __restrict__ out) {
    int gi = blockIdx.x * 256 + threadIdx.x;
    if (gi >= N_GRAPHS) return;
    const float* hidden = g_agg + (size_t)N_GRAPHS * 128 + N_GRAPHS;
    float z = bc2[0];
#pragma unroll 8
    for (int k = 0; k < 64; ++k) z = fmaf(hidden[gi * 64 + k], Wc2[k], z);
    out[gi] = z;
}

// ---------------- launch ----------------

extern "C" void kernel_launch(void* const* d_in, const int* in_sizes, int n_in,
                              void* d_out, int out_size, void* d_ws, size_t ws_size,
                              hipStream_t stream) {
    const float* x     = (const float*)d_in[0];
    const int*   ei    = (const int*)d_in[1];
    const int*   batch = (const int*)d_in[2];
    const float* W1 = (const float*)d_in[3];
    const float* b1 = (const float*)d_in[4];
    const float* g1 = (const float*)d_in[5];
    const float* bt1= (const float*)d_in[6];
    const float* rm1= (const float*)d_in[7];
    const float* rv1= (const float*)d_in[8];
    const float* W2 = (const float*)d_in[9];
    const float* b2 = (const float*)d_in[10];
    const float* g2 = (const float*)d_in[11];
    const float* bt2= (const float*)d_in[12];
    const float* rm2= (const float*)d_in[13];
    const float* rv2= (const float*)d_in[14];
    const float* W3 = (const float*)d_in[15];
    const float* b3 = (const float*)d_in[16];
    const float* g3 = (const float*)d_in[17];
    const float* bt3= (const float*)d_in[18];
    const float* rm3= (const float*)d_in[19];
    const float* rv3= (const float*)d_in[20];
    const float* Wc1= (const float*)d_in[21];
    const float* bc1= (const float*)d_in[22];
    const float* Wc2= (const float*)d_in[23];
    const float* bc2= (const float*)d_in[24];
    float* outp = (float*)d_out;
    (void)d_ws; (void)ws_size; (void)n_in; (void)in_sizes;

    const int* srcp = ei;
    const int* dstp = ei + N_EDGES;

    // gcn norm: deg -> dinv (in place in g_dinv)
    k_fill1<<<(N_NODES + 255) / 256, 256, 0, stream>>>(N_NODES);
    k_edge_deg<<<(N_EDGES + 255) / 256, 256, 0, stream>>>(dstp);
    k_rsqrt_inplace<<<(N_NODES + 255) / 256, 256, 0, stream>>>(N_NODES);

    // layer 1: aggregate the 7-dim input first, then 7->128 linear + BN + ReLU
    k_p7<<<(N_NODES + 255) / 256, 256, 0, stream>>>(x);
    k_edge_agg7<<<(N_EDGES + 255) / 256, 256, 0, stream>>>(srcp, dstp);
    k_lin1_bn_relu<<<(N_NODES * 128) / 256, 256, 0, stream>>>(W1, b1, g1, bt1, rm1, rv1);

    // layer 2: g_h(q1) -> g_agg -> g_h(q2)
    k_selfcopy<<<(N_NODES * 32) / 256, 256, 0, stream>>>();
    k_edge_agg<<<N_EDGES / 8, 256, 0, stream>>>(srcp, dstp);
    k_gemm_bn_relu<true><<<N_NODES / 64, 256, 0, stream>>>(W2, b2, g2, bt2, rm2, rv2);

    // layer 3: g_h(q2) -> g_agg -> g_h(h3, no premult)
    k_selfcopy<<<(N_NODES * 32) / 256, 256, 0, stream>>>();
    k_edge_agg<<<N_EDGES / 8, 256, 0, stream>>>(srcp, dstp);
    k_gemm_bn_relu<false><<<N_NODES / 64, 256, 0, stream>>>(W3, b3, g3, bt3, rm3, rv3);

    // mean pool + head MLP (g_agg region is dead -> reuse for pooled/cnt/hidden)
    k_zero_pool<<<(N_GRAPHS * 129 + 255) / 256, 256, 0, stream>>>();
    k_pool<<<(N_NODES * 32) / 256, 256, 0, stream>>>(batch);
    k_cnt<<<(N_NODES + 255) / 256, 256, 0, stream>>>(batch);
    k_head1<<<(N_GRAPHS * 64) / 256, 256, 0, stream>>>(Wc1, bc1);
    k_head2<<<(N_GRAPHS + 255) / 256, 256, 0, stream>>>(Wc2, bc2, outp);
}

// Round 4
// 3247.239 us; speedup vs baseline: 6.7069x; 6.7069x over previous
//
#include <hip/hip_runtime.h>

#define N_NODES 1000000
#define N_EDGES 4000000
#define N_GRAPHS 32768
#define BN_EPS 1e-5f
#define NBLK1 3907   // ceil(N_NODES/256) for the scan

// ---------------------------------------------------------------------------
// Scratch in static device globals (loader BSS): ws_size proved too small for
// the ~1 GB of intermediates this pipeline needs. Graph-capture safe; every
// element read is written earlier in the SAME kernel_launch call.
// ---------------------------------------------------------------------------
__device__ float g_h[128000000];        // 512 MB node features (q / h)
__device__ float g_agg[128000000];      // 512 MB aggregation buffer (+ pool/head scratch)
__device__ float g_dinv[N_NODES];       // deg^{-1/2}
__device__ int   g_rowcnt[N_NODES];     // in-degree histogram / scatter cursor
__device__ int   g_row_start[N_NODES + 1];
__device__ int   g_csr_src[N_EDGES];    // src indices sorted by dst
__device__ int   g_part[NBLK1];         // scan partials
__device__ int   g_gstart[N_GRAPHS + 1];// graph boundaries in sorted batch

// ---------------- CSR build: histogram -> dinv -> scan -> scatter -----------

__global__ __launch_bounds__(256) void k_zero_cnt() {
    int i = blockIdx.x * 256 + threadIdx.x;
    if (i < N_NODES) g_rowcnt[i] = 0;
}

__global__ __launch_bounds__(256) void k_hist(const int* __restrict__ dst) {
    int e = blockIdx.x * 256 + threadIdx.x;
    if (e < N_EDGES) atomicAdd(&g_rowcnt[dst[e]], 1);
}

__global__ __launch_bounds__(256) void k_dinv() {
    int i = blockIdx.x * 256 + threadIdx.x;
    if (i < N_NODES) g_dinv[i] = rsqrtf((float)(1 + g_rowcnt[i]));  // +1 self-loop
}

// exclusive scan of g_rowcnt into g_row_start, block partials to g_part
__global__ __launch_bounds__(256) void k_scan1() {
    __shared__ int sh[256];
    int i = blockIdx.x * 256 + threadIdx.x;
    int v = (i < N_NODES) ? g_rowcnt[i] : 0;
    sh[threadIdx.x] = v;
    __syncthreads();
#pragma unroll
    for (int off = 1; off < 256; off <<= 1) {
        int t = (threadIdx.x >= off) ? sh[threadIdx.x - off] : 0;
        __syncthreads();
        sh[threadIdx.x] += t;
        __syncthreads();
    }
    int incl = sh[threadIdx.x];
    if (i < N_NODES) g_row_start[i] = incl - v;   // exclusive, block-local
    if (threadIdx.x == 255) g_part[blockIdx.x] = incl;
}

// single block: exclusive scan of NBLK1 partials in place
__global__ __launch_bounds__(256) void k_scan2() {
    __shared__ int sh[256];
    int base = threadIdx.x * 16;
    int local[16];
    int s = 0;
#pragma unroll
    for (int k = 0; k < 16; ++k) {
        local[k] = (base + k < NBLK1) ? g_part[base + k] : 0;
        s += local[k];
    }
    sh[threadIdx.x] = s;
    __syncthreads();
#pragma unroll
    for (int off = 1; off < 256; off <<= 1) {
        int t = (threadIdx.x >= off) ? sh[threadIdx.x - off] : 0;
        __syncthreads();
        sh[threadIdx.x] += t;
        __syncthreads();
    }
    int carry = sh[threadIdx.x] - s;   // exclusive base for this chunk
#pragma unroll
    for (int k = 0; k < 16; ++k) {
        if (base + k < NBLK1) {
            int t = local[k];
            g_part[base + k] = carry;
            carry += t;
        }
    }
}

// add block bases; zero rowcnt for scatter reuse; set sentinel
__global__ __launch_bounds__(256) void k_scan3() {
    int i = blockIdx.x * 256 + threadIdx.x;
    if (i < N_NODES) {
        g_row_start[i] += g_part[blockIdx.x];
        g_rowcnt[i] = 0;
    }
    if (i == 0) g_row_start[N_NODES] = N_EDGES;
}

__global__ __launch_bounds__(256) void k_scatter(const int* __restrict__ src,
                                                 const int* __restrict__ dst) {
    int e = blockIdx.x * 256 + threadIdx.x;
    if (e >= N_EDGES) return;
    int d = dst[e];
    int pos = g_row_start[d] + atomicAdd(&g_rowcnt[d], 1);
    g_csr_src[pos] = src[e];
}

// ---------------- layer 1: CSR gather of 7-dim input ------------------------
// agg7[d] = dinv[d]*x[d] + sum_{s in N(d)} dinv[s]*x[s]   (stored in g_agg)

__global__ __launch_bounds__(256) void k_agg7_csr(const float* __restrict__ x) {
    int t = blockIdx.x * 256 + threadIdx.x;
    int i = t >> 3;            // node, 8 lanes each
    int c = t & 7;             // 0..7, c<7 active
    if (i >= N_NODES || c >= 7) return;
    float acc = g_dinv[i] * x[i * 7 + c];
    int e0 = g_row_start[i], e1 = g_row_start[i + 1];
    for (int e = e0; e < e1; ++e) {
        int s = g_csr_src[e];
        acc = fmaf(g_dinv[s], x[s * 7 + c], acc);
    }
    g_agg[i * 7 + c] = acc;
}

// z = agg7 . W1 ; h1 = relu(bn(dinv*z + b)) ; store q1 = dinv*h1
__global__ __launch_bounds__(256) void k_lin1_bn_relu(const float* __restrict__ W,
                                                      const float* __restrict__ b,
                                                      const float* __restrict__ g,
                                                      const float* __restrict__ bt,
                                                      const float* __restrict__ rm,
                                                      const float* __restrict__ rv) {
    int t = blockIdx.x * 256 + threadIdx.x;   // node*128 + c
    int i = t >> 7, c = t & 127;
    if (i >= N_NODES) return;
    const float* agg7 = g_agg;
    float z = 0.f;
#pragma unroll
    for (int k = 0; k < 7; ++k) z = fmaf(agg7[i * 7 + k], W[k * 128 + c], z);
    float dv = g_dinv[i];
    z *= dv;
    float sc  = g[c] * rsqrtf(rv[c] + BN_EPS);
    float off = fmaf(b[c] - rm[c], sc, bt[c]);
    g_h[(size_t)i * 128 + c] = fmaxf(fmaf(z, sc, off), 0.f) * dv;
}

// ---------------- 128-dim CSR gather (layers 2,3) ---------------------------
// agg[d] = q[d] + sum_{s in N(d)} q[s]   (q premultiplied by dinv)
// 32 lanes per node (float4 each), 8 nodes per block.

__global__ __launch_bounds__(256) void k_agg_csr() {
    int t = blockIdx.x * 256 + threadIdx.x;
    int i = t >> 5;
    if (i >= N_NODES) return;
    int c = (t & 31) << 2;
    float4 acc = *(const float4*)(g_h + (size_t)i * 128 + c);   // self term
    int e0 = g_row_start[i], e1 = g_row_start[i + 1];
    for (int e = e0; e < e1; ++e) {
        int s = g_csr_src[e];
        float4 v = *(const float4*)(g_h + (size_t)s * 128 + c);
        acc.x += v.x; acc.y += v.y; acc.z += v.z; acc.w += v.w;
    }
    *(float4*)(g_agg + (size_t)i * 128 + c) = acc;
}

// ---------------- fused 128x128 GEMM + dinv + bias + BN + ReLU --------------

template <bool PRE>
__global__ __launch_bounds__(256) void k_gemm_bn_relu(const float* __restrict__ W,
                                                      const float* __restrict__ b,
                                                      const float* __restrict__ g,
                                                      const float* __restrict__ bt,
                                                      const float* __restrict__ rm,
                                                      const float* __restrict__ rv) {
    __shared__ float As[64][132];
    __shared__ float Ws[32][128];
    const int tid = threadIdx.x;
    const size_t row0 = (size_t)blockIdx.x * 64;

#pragma unroll
    for (int i = 0; i < 8; ++i) {
        int t = tid + i * 256;
        int r = t >> 5, k4 = (t & 31) << 2;
        *(float4*)(&As[r][k4]) = *(const float4*)(g_agg + (row0 + r) * 128 + k4);
    }

    float acc[4][8];
#pragma unroll
    for (int r = 0; r < 4; ++r)
#pragma unroll
        for (int j = 0; j < 8; ++j) acc[r][j] = 0.f;

    const int tr = tid >> 4;
    const int tc = tid & 15;

    for (int kb = 0; kb < 4; ++kb) {
        __syncthreads();
#pragma unroll
        for (int i = 0; i < 4; ++i) {
            int t = tid + i * 256;
            int r = t >> 5, k4 = (t & 31) << 2;
            *(float4*)(&Ws[r][k4]) = *(const float4*)(W + (size_t)(kb * 32 + r) * 128 + k4);
        }
        __syncthreads();
#pragma unroll
        for (int k = 0; k < 32; ++k) {
            float a[4];
#pragma unroll
            for (int r = 0; r < 4; ++r) a[r] = As[tr * 4 + r][kb * 32 + k];
            float4 w0 = *(const float4*)(&Ws[k][tc * 4]);
            float4 w1 = *(const float4*)(&Ws[k][64 + tc * 4]);
            float w[8] = {w0.x, w0.y, w0.z, w0.w, w1.x, w1.y, w1.z, w1.w};
#pragma unroll
            for (int r = 0; r < 4; ++r)
#pragma unroll
                for (int j = 0; j < 8; ++j)
                    acc[r][j] = fmaf(a[r], w[j], acc[r][j]);
        }
    }

    float4 dv4 = *(const float4*)(g_dinv + row0 + tr * 4);
    float dv[4] = {dv4.x, dv4.y, dv4.z, dv4.w};

#pragma unroll
    for (int half = 0; half < 2; ++half) {
        int cb = half * 64 + tc * 4;
        float s0 = g[cb + 0] * rsqrtf(rv[cb + 0] + BN_EPS);
        float s1 = g[cb + 1] * rsqrtf(rv[cb + 1] + BN_EPS);
        float s2 = g[cb + 2] * rsqrtf(rv[cb + 2] + BN_EPS);
        float s3 = g[cb + 3] * rsqrtf(rv[cb + 3] + BN_EPS);
        float o0 = fmaf(b[cb + 0] - rm[cb + 0], s0, bt[cb + 0]);
        float o1 = fmaf(b[cb + 1] - rm[cb + 1], s1, bt[cb + 1]);
        float o2 = fmaf(b[cb + 2] - rm[cb + 2], s2, bt[cb + 2]);
        float o3 = fmaf(b[cb + 3] - rm[cb + 3], s3, bt[cb + 3]);
#pragma unroll
        for (int r = 0; r < 4; ++r) {
            float pm = PRE ? dv[r] : 1.0f;
            float4 o;
            o.x = fmaxf(fmaf(acc[r][half * 4 + 0] * dv[r], s0, o0), 0.f) * pm;
            o.y = fmaxf(fmaf(acc[r][half * 4 + 1] * dv[r], s1, o1), 0.f) * pm;
            o.z = fmaxf(fmaf(acc[r][half * 4 + 2] * dv[r], s2, o2), 0.f) * pm;
            o.w = fmaxf(fmaf(acc[r][half * 4 + 3] * dv[r], s3, o3), 0.f) * pm;
            *(float4*)(g_h + (row0 + tr * 4 + r) * 128 + cb) = o;
        }
    }
}

// ---------------- pooling (segment mean over sorted batch) + head -----------
// pooled = g_agg[0 .. 4.19M), hidden = g_agg[4.5M .. 6.6M)

__global__ __launch_bounds__(256) void k_gstart(const int* __restrict__ batch) {
    int gidx = blockIdx.x * 256 + threadIdx.x;
    if (gidx > N_GRAPHS) return;
    int lo = 0, hi = N_NODES;
    while (lo < hi) {                       // lower_bound(batch, gidx)
        int mid = (lo + hi) >> 1;
        if (batch[mid] < gidx) lo = mid + 1; else hi = mid;
    }
    g_gstart[gidx] = lo;
}

__global__ __launch_bounds__(256) void k_pool_seg() {
    int t = blockIdx.x * 256 + threadIdx.x;
    int gidx = t >> 5;
    if (gidx >= N_GRAPHS) return;
    int c = (t & 31) << 2;
    int s0 = g_gstart[gidx], s1 = g_gstart[gidx + 1];
    float4 acc = make_float4(0.f, 0.f, 0.f, 0.f);
    for (int i = s0; i < s1; ++i) {
        float4 v = *(const float4*)(g_h + (size_t)i * 128 + c);
        acc.x += v.x; acc.y += v.y; acc.z += v.z; acc.w += v.w;
    }
    float inv = 1.0f / (float)max(s1 - s0, 1);
    acc.x *= inv; acc.y *= inv; acc.z *= inv; acc.w *= inv;
    *(float4*)(g_agg + (size_t)gidx * 128 + c) = acc;
}

__global__ __launch_bounds__(256) void k_head1(const float* __restrict__ Wc1,
                                               const float* __restrict__ bc1) {
    int t = blockIdx.x * 256 + threadIdx.x;  // g*64 + c
    int gi = t >> 6, c = t & 63;
    if (gi >= N_GRAPHS) return;
    const float* pooled = g_agg;
    float* hidden = g_agg + (size_t)N_GRAPHS * 128 + 65536;
    float z = 0.f;
#pragma unroll 8
    for (int k = 0; k < 128; ++k) z = fmaf(pooled[gi * 128 + k], Wc1[k * 64 + c], z);
    hidden[t] = fmaxf(z + bc1[c], 0.f);
}

__global__ __launch_bounds__(256) void k_head2(const float* __restrict__ Wc2,
                                               const float* __restrict__ bc2,
                                               float* __restrict__ out) {
    int gi = blockIdx.x * 256 + threadIdx.x;
    if (gi >= N_GRAPHS) return;
    const float* hidden = g_agg + (size_t)N_GRAPHS * 128 + 65536;
    float z = bc2[0];
#pragma unroll 8
    for (int k = 0; k < 64; ++k) z = fmaf(hidden[gi * 64 + k], Wc2[k], z);
    out[gi] = z;
}

// ---------------- launch ----------------

extern "C" void kernel_launch(void* const* d_in, const int* in_sizes, int n_in,
                              void* d_out, int out_size, void* d_ws, size_t ws_size,
                              hipStream_t stream) {
    const float* x     = (const float*)d_in[0];
    const int*   ei    = (const int*)d_in[1];
    const int*   batch = (const int*)d_in[2];
    const float* W1 = (const float*)d_in[3];
    const float* b1 = (const float*)d_in[4];
    const float* g1 = (const float*)d_in[5];
    const float* bt1= (const float*)d_in[6];
    const float* rm1= (const float*)d_in[7];
    const float* rv1= (const float*)d_in[8];
    const float* W2 = (const float*)d_in[9];
    const float* b2 = (const float*)d_in[10];
    const float* g2 = (const float*)d_in[11];
    const float* bt2= (const float*)d_in[12];
    const float* rm2= (const float*)d_in[13];
    const float* rv2= (const float*)d_in[14];
    const float* W3 = (const float*)d_in[15];
    const float* b3 = (const float*)d_in[16];
    const float* g3 = (const float*)d_in[17];
    const float* bt3= (const float*)d_in[18];
    const float* rm3= (const float*)d_in[19];
    const float* rv3= (const float*)d_in[20];
    const float* Wc1= (const float*)d_in[21];
    const float* bc1= (const float*)d_in[22];
    const float* Wc2= (const float*)d_in[23];
    const float* bc2= (const float*)d_in[24];
    float* outp = (float*)d_out;
    (void)d_ws; (void)ws_size; (void)n_in; (void)in_sizes;

    const int* srcp = ei;
    const int* dstp = ei + N_EDGES;

    // CSR build (by dst) + dinv
    k_zero_cnt<<<NBLK1, 256, 0, stream>>>();
    k_hist<<<(N_EDGES + 255) / 256, 256, 0, stream>>>(dstp);
    k_dinv<<<NBLK1, 256, 0, stream>>>();
    k_scan1<<<NBLK1, 256, 0, stream>>>();
    k_scan2<<<1, 256, 0, stream>>>();
    k_scan3<<<NBLK1, 256, 0, stream>>>();
    k_scatter<<<(N_EDGES + 255) / 256, 256, 0, stream>>>(srcp, dstp);

    // graph boundaries for pooling (independent; cheap)
    k_gstart<<<(N_GRAPHS + 1 + 255) / 256, 256, 0, stream>>>(batch);

    // layer 1: gather 7-dim input, then 7->128 linear + BN + ReLU
    k_agg7_csr<<<(N_NODES * 8) / 256, 256, 0, stream>>>(x);
    k_lin1_bn_relu<<<(N_NODES * 128) / 256, 256, 0, stream>>>(W1, b1, g1, bt1, rm1, rv1);

    // layer 2: g_h(q1) -> gather -> g_agg -> gemm -> g_h(q2)
    k_agg_csr<<<(N_NODES * 32) / 256, 256, 0, stream>>>();
    k_gemm_bn_relu<true><<<N_NODES / 64, 256, 0, stream>>>(W2, b2, g2, bt2, rm2, rv2);

    // layer 3
    k_agg_csr<<<(N_NODES * 32) / 256, 256, 0, stream>>>();
    k_gemm_bn_relu<false><<<N_NODES / 64, 256, 0, stream>>>(W3, b3, g3, bt3, rm3, rv3);

    // segment-mean pool + head MLP
    k_pool_seg<<<(N_GRAPHS * 32) / 256, 256, 0, stream>>>();
    k_head1<<<(N_GRAPHS * 64) / 256, 256, 0, stream>>>(Wc1, bc1);
    k_head2<<<(N_GRAPHS + 255) / 256, 256, 0, stream>>>(Wc2, bc2, outp);
}

// Round 5
// 2920.884 us; speedup vs baseline: 7.4563x; 1.1117x over previous
//
#include <hip/hip_runtime.h>
#include <hip/hip_fp16.h>

#define N_NODES 1000000
#define N_EDGES 4000000
#define N_GRAPHS 32768
#define BN_EPS 1e-5f
#define NBLK1 3907   // ceil(N_NODES/256) for the scan

// ---------------------------------------------------------------------------
// Scratch in static device globals (loader BSS): ws_size proved too small.
// g_h is fp16 (256 MB) so the edge-gather working set fits the 256 MB L3;
// ALL arithmetic stays f32 — fp16 is storage-only (3 roundings total).
// ---------------------------------------------------------------------------
__device__ __half g_h[128000000];       // 256 MB node features (q / h), fp16
__device__ float  g_agg[128000000];     // 512 MB aggregation buffer (+ pool/head scratch)
__device__ float  g_dinv[N_NODES];      // deg^{-1/2}
__device__ int    g_rowcnt[N_NODES];    // in-degree histogram / scatter cursor
__device__ int    g_row_start[N_NODES + 1];
__device__ int    g_csr_src[N_EDGES];   // src indices sorted by dst
__device__ int    g_part[NBLK1];        // scan partials
__device__ int    g_gstart[N_GRAPHS + 1];

// ---------------- fp16 <-> f32 vector helpers ----------------

__device__ __forceinline__ float4 ld_h4(const __half* p) {
    uint2 raw;
    __builtin_memcpy(&raw, p, 8);        // one 8-byte load
    __half2 h01, h23;
    __builtin_memcpy(&h01, &raw.x, 4);
    __builtin_memcpy(&h23, &raw.y, 4);
    float2 a = __half22float2(h01);
    float2 b = __half22float2(h23);
    return make_float4(a.x, a.y, b.x, b.y);
}

__device__ __forceinline__ void st_h4(__half* p, float4 v) {
    __half2 h01 = __floats2half2_rn(v.x, v.y);
    __half2 h23 = __floats2half2_rn(v.z, v.w);
    uint2 raw;
    __builtin_memcpy(&raw.x, &h01, 4);
    __builtin_memcpy(&raw.y, &h23, 4);
    __builtin_memcpy(p, &raw, 8);        // one 8-byte store
}

// ---------------- CSR build: histogram -> dinv -> scan -> scatter -----------

__global__ __launch_bounds__(256) void k_zero_cnt() {
    int i = blockIdx.x * 256 + threadIdx.x;
    if (i < N_NODES) g_rowcnt[i] = 0;
}

__global__ __launch_bounds__(256) void k_hist(const int* __restrict__ dst) {
    int e = blockIdx.x * 256 + threadIdx.x;
    if (e < N_EDGES) atomicAdd(&g_rowcnt[dst[e]], 1);
}

__global__ __launch_bounds__(256) void k_dinv() {
    int i = blockIdx.x * 256 + threadIdx.x;
    if (i < N_NODES) g_dinv[i] = rsqrtf((float)(1 + g_rowcnt[i]));  // +1 self-loop
}

__global__ __launch_bounds__(256) void k_scan1() {
    __shared__ int sh[256];
    int i = blockIdx.x * 256 + threadIdx.x;
    int v = (i < N_NODES) ? g_rowcnt[i] : 0;
    sh[threadIdx.x] = v;
    __syncthreads();
#pragma unroll
    for (int off = 1; off < 256; off <<= 1) {
        int t = (threadIdx.x >= off) ? sh[threadIdx.x - off] : 0;
        __syncthreads();
        sh[threadIdx.x] += t;
        __syncthreads();
    }
    int incl = sh[threadIdx.x];
    if (i < N_NODES) g_row_start[i] = incl - v;
    if (threadIdx.x == 255) g_part[blockIdx.x] = incl;
}

__global__ __launch_bounds__(256) void k_scan2() {
    __shared__ int sh[256];
    int base = threadIdx.x * 16;
    int local[16];
    int s = 0;
#pragma unroll
    for (int k = 0; k < 16; ++k) {
        local[k] = (base + k < NBLK1) ? g_part[base + k] : 0;
        s += local[k];
    }
    sh[threadIdx.x] = s;
    __syncthreads();
#pragma unroll
    for (int off = 1; off < 256; off <<= 1) {
        int t = (threadIdx.x >= off) ? sh[threadIdx.x - off] : 0;
        __syncthreads();
        sh[threadIdx.x] += t;
        __syncthreads();
    }
    int carry = sh[threadIdx.x] - s;
#pragma unroll
    for (int k = 0; k < 16; ++k) {
        if (base + k < NBLK1) {
            int t = local[k];
            g_part[base + k] = carry;
            carry += t;
        }
    }
}

__global__ __launch_bounds__(256) void k_scan3() {
    int i = blockIdx.x * 256 + threadIdx.x;
    if (i < N_NODES) {
        g_row_start[i] += g_part[blockIdx.x];
        g_rowcnt[i] = 0;
    }
    if (i == 0) g_row_start[N_NODES] = N_EDGES;
}

__global__ __launch_bounds__(256) void k_scatter(const int* __restrict__ src,
                                                 const int* __restrict__ dst) {
    int e = blockIdx.x * 256 + threadIdx.x;
    if (e >= N_EDGES) return;
    int d = dst[e];
    int pos = g_row_start[d] + atomicAdd(&g_rowcnt[d], 1);
    g_csr_src[pos] = src[e];
}

// ---------------- layer 1: CSR gather of 7-dim input ------------------------

__global__ __launch_bounds__(256) void k_agg7_csr(const float* __restrict__ x) {
    int t = blockIdx.x * 256 + threadIdx.x;
    int i = t >> 3;
    int c = t & 7;
    if (i >= N_NODES || c >= 7) return;
    float acc = g_dinv[i] * x[i * 7 + c];
    int e0 = g_row_start[i], e1 = g_row_start[i + 1];
    for (int e = e0; e < e1; ++e) {
        int s = g_csr_src[e];
        acc = fmaf(g_dinv[s], x[s * 7 + c], acc);
    }
    g_agg[i * 7 + c] = acc;
}

// z = agg7 . W1 ; h1 = relu(bn(dinv*z + b)) ; store q1 = dinv*h1 (fp16)
__global__ __launch_bounds__(256) void k_lin1_bn_relu(const float* __restrict__ W,
                                                      const float* __restrict__ b,
                                                      const float* __restrict__ g,
                                                      const float* __restrict__ bt,
                                                      const float* __restrict__ rm,
                                                      const float* __restrict__ rv) {
    int t = blockIdx.x * 256 + threadIdx.x;
    int i = t >> 7, c = t & 127;
    if (i >= N_NODES) return;
    const float* agg7 = g_agg;
    float z = 0.f;
#pragma unroll
    for (int k = 0; k < 7; ++k) z = fmaf(agg7[i * 7 + k], W[k * 128 + c], z);
    float dv = g_dinv[i];
    z *= dv;
    float sc  = g[c] * rsqrtf(rv[c] + BN_EPS);
    float off = fmaf(b[c] - rm[c], sc, bt[c]);
    g_h[(size_t)i * 128 + c] = __float2half_rn(fmaxf(fmaf(z, sc, off), 0.f) * dv);
}

// ---------------- 128-dim CSR gather (layers 2,3) ---------------------------
// agg[d] = q[d] + sum_{s in N(d)} q[s]; q fp16-stored, f32 accumulate.

__global__ __launch_bounds__(256) void k_agg_csr() {
    int t = blockIdx.x * 256 + threadIdx.x;
    int i = t >> 5;
    if (i >= N_NODES) return;
    int c = (t & 31) << 2;
    float4 acc = ld_h4(g_h + (size_t)i * 128 + c);   // self term
    int e0 = g_row_start[i], e1 = g_row_start[i + 1];
    for (int e = e0; e < e1; ++e) {
        int s = g_csr_src[e];
        float4 v = ld_h4(g_h + (size_t)s * 128 + c);
        acc.x += v.x; acc.y += v.y; acc.z += v.z; acc.w += v.w;
    }
    *(float4*)(g_agg + (size_t)i * 128 + c) = acc;
}

// ---------------- fused 128x128 GEMM + dinv + bias + BN + ReLU --------------

template <bool PRE>
__global__ __launch_bounds__(256) void k_gemm_bn_relu(const float* __restrict__ W,
                                                      const float* __restrict__ b,
                                                      const float* __restrict__ g,
                                                      const float* __restrict__ bt,
                                                      const float* __restrict__ rm,
                                                      const float* __restrict__ rv) {
    __shared__ float As[64][132];
    __shared__ float Ws[32][128];
    const int tid = threadIdx.x;
    const size_t row0 = (size_t)blockIdx.x * 64;

#pragma unroll
    for (int i = 0; i < 8; ++i) {
        int t = tid + i * 256;
        int r = t >> 5, k4 = (t & 31) << 2;
        *(float4*)(&As[r][k4]) = *(const float4*)(g_agg + (row0 + r) * 128 + k4);
    }

    float acc[4][8];
#pragma unroll
    for (int r = 0; r < 4; ++r)
#pragma unroll
        for (int j = 0; j < 8; ++j) acc[r][j] = 0.f;

    const int tr = tid >> 4;
    const int tc = tid & 15;

    for (int kb = 0; kb < 4; ++kb) {
        __syncthreads();
#pragma unroll
        for (int i = 0; i < 4; ++i) {
            int t = tid + i * 256;
            int r = t >> 5, k4 = (t & 31) << 2;
            *(float4*)(&Ws[r][k4]) = *(const float4*)(W + (size_t)(kb * 32 + r) * 128 + k4);
        }
        __syncthreads();
#pragma unroll
        for (int k = 0; k < 32; ++k) {
            float a[4];
#pragma unroll
            for (int r = 0; r < 4; ++r) a[r] = As[tr * 4 + r][kb * 32 + k];
            float4 w0 = *(const float4*)(&Ws[k][tc * 4]);
            float4 w1 = *(const float4*)(&Ws[k][64 + tc * 4]);
            float w[8] = {w0.x, w0.y, w0.z, w0.w, w1.x, w1.y, w1.z, w1.w};
#pragma unroll
            for (int r = 0; r < 4; ++r)
#pragma unroll
                for (int j = 0; j < 8; ++j)
                    acc[r][j] = fmaf(a[r], w[j], acc[r][j]);
        }
    }

    float4 dv4 = *(const float4*)(g_dinv + row0 + tr * 4);
    float dv[4] = {dv4.x, dv4.y, dv4.z, dv4.w};

#pragma unroll
    for (int half = 0; half < 2; ++half) {
        int cb = half * 64 + tc * 4;
        float s0 = g[cb + 0] * rsqrtf(rv[cb + 0] + BN_EPS);
        float s1 = g[cb + 1] * rsqrtf(rv[cb + 1] + BN_EPS);
        float s2 = g[cb + 2] * rsqrtf(rv[cb + 2] + BN_EPS);
        float s3 = g[cb + 3] * rsqrtf(rv[cb + 3] + BN_EPS);
        float o0 = fmaf(b[cb + 0] - rm[cb + 0], s0, bt[cb + 0]);
        float o1 = fmaf(b[cb + 1] - rm[cb + 1], s1, bt[cb + 1]);
        float o2 = fmaf(b[cb + 2] - rm[cb + 2], s2, bt[cb + 2]);
        float o3 = fmaf(b[cb + 3] - rm[cb + 3], s3, bt[cb + 3]);
#pragma unroll
        for (int r = 0; r < 4; ++r) {
            float pm = PRE ? dv[r] : 1.0f;
            float4 o;
            o.x = fmaxf(fmaf(acc[r][half * 4 + 0] * dv[r], s0, o0), 0.f) * pm;
            o.y = fmaxf(fmaf(acc[r][half * 4 + 1] * dv[r], s1, o1), 0.f) * pm;
            o.z = fmaxf(fmaf(acc[r][half * 4 + 2] * dv[r], s2, o2), 0.f) * pm;
            o.w = fmaxf(fmaf(acc[r][half * 4 + 3] * dv[r], s3, o3), 0.f) * pm;
            st_h4(g_h + (row0 + tr * 4 + r) * 128 + cb, o);
        }
    }
}

// ---------------- pooling (segment mean over sorted batch) + head -----------

__global__ __launch_bounds__(256) void k_gstart(const int* __restrict__ batch) {
    int gidx = blockIdx.x * 256 + threadIdx.x;
    if (gidx > N_GRAPHS) return;
    int lo = 0, hi = N_NODES;
    while (lo < hi) {
        int mid = (lo + hi) >> 1;
        if (batch[mid] < gidx) lo = mid + 1; else hi = mid;
    }
    g_gstart[gidx] = lo;
}

__global__ __launch_bounds__(256) void k_pool_seg() {
    int t = blockIdx.x * 256 + threadIdx.x;
    int gidx = t >> 5;
    if (gidx >= N_GRAPHS) return;
    int c = (t & 31) << 2;
    int s0 = g_gstart[gidx], s1 = g_gstart[gidx + 1];
    float4 acc = make_float4(0.f, 0.f, 0.f, 0.f);
    for (int i = s0; i < s1; ++i) {
        float4 v = ld_h4(g_h + (size_t)i * 128 + c);
        acc.x += v.x; acc.y += v.y; acc.z += v.z; acc.w += v.w;
    }
    float inv = 1.0f / (float)max(s1 - s0, 1);
    acc.x *= inv; acc.y *= inv; acc.z *= inv; acc.w *= inv;
    *(float4*)(g_agg + (size_t)gidx * 128 + c) = acc;
}

__global__ __launch_bounds__(256) void k_head1(const float* __restrict__ Wc1,
                                               const float* __restrict__ bc1) {
    int t = blockIdx.x * 256 + threadIdx.x;
    int gi = t >> 6, c = t & 63;
    if (gi >= N_GRAPHS) return;
    const float* pooled = g_agg;
    float* hidden = g_agg + (size_t)N_GRAPHS * 128 + 65536;
    float z = 0.f;
#pragma unroll 8
    for (int k = 0; k < 128; ++k) z = fmaf(pooled[gi * 128 + k], Wc1[k * 64 + c], z);
    hidden[t] = fmaxf(z + bc1[c], 0.f);
}

__global__ __launch_bounds__(256) void k_head2(const float* __restrict__ Wc2,
                                               const float* __restrict__ bc2,
                                               float* __restrict__ out) {
    int gi = blockIdx.x * 256 + threadIdx.x;
    if (gi >= N_GRAPHS) return;
    const float* hidden = g_agg + (size_t)N_GRAPHS * 128 + 65536;
    float z = bc2[0];
#pragma unroll 8
    for (int k = 0; k < 64; ++k) z = fmaf(hidden[gi * 64 + k], Wc2[k], z);
    out[gi] = z;
}

// ---------------- launch ----------------

extern "C" void kernel_launch(void* const* d_in, const int* in_sizes, int n_in,
                              void* d_out, int out_size, void* d_ws, size_t ws_size,
                              hipStream_t stream) {
    const float* x     = (const float*)d_in[0];
    const int*   ei    = (const int*)d_in[1];
    const int*   batch = (const int*)d_in[2];
    const float* W1 = (const float*)d_in[3];
    const float* b1 = (const float*)d_in[4];
    const float* g1 = (const float*)d_in[5];
    const float* bt1= (const float*)d_in[6];
    const float* rm1= (const float*)d_in[7];
    const float* rv1= (const float*)d_in[8];
    const float* W2 = (const float*)d_in[9];
    const float* b2 = (const float*)d_in[10];
    const float* g2 = (const float*)d_in[11];
    const float* bt2= (const float*)d_in[12];
    const float* rm2= (const float*)d_in[13];
    const float* rv2= (const float*)d_in[14];
    const float* W3 = (const float*)d_in[15];
    const float* b3 = (const float*)d_in[16];
    const float* g3 = (const float*)d_in[17];
    const float* bt3= (const float*)d_in[18];
    const float* rm3= (const float*)d_in[19];
    const float* rv3= (const float*)d_in[20];
    const float* Wc1= (const float*)d_in[21];
    const float* bc1= (const float*)d_in[22];
    const float* Wc2= (const float*)d_in[23];
    const float* bc2= (const float*)d_in[24];
    float* outp = (float*)d_out;
    (void)d_ws; (void)ws_size; (void)n_in; (void)in_sizes;

    const int* srcp = ei;
    const int* dstp = ei + N_EDGES;

    // CSR build (by dst) + dinv
    k_zero_cnt<<<NBLK1, 256, 0, stream>>>();
    k_hist<<<(N_EDGES + 255) / 256, 256, 0, stream>>>(dstp);
    k_dinv<<<NBLK1, 256, 0, stream>>>();
    k_scan1<<<NBLK1, 256, 0, stream>>>();
    k_scan2<<<1, 256, 0, stream>>>();
    k_scan3<<<NBLK1, 256, 0, stream>>>();
    k_scatter<<<(N_EDGES + 255) / 256, 256, 0, stream>>>(srcp, dstp);

    // graph boundaries for pooling
    k_gstart<<<(N_GRAPHS + 1 + 255) / 256, 256, 0, stream>>>(batch);

    // layer 1
    k_agg7_csr<<<(N_NODES * 8) / 256, 256, 0, stream>>>(x);
    k_lin1_bn_relu<<<(N_NODES * 128) / 256, 256, 0, stream>>>(W1, b1, g1, bt1, rm1, rv1);

    // layer 2
    k_agg_csr<<<(N_NODES * 32) / 256, 256, 0, stream>>>();
    k_gemm_bn_relu<true><<<N_NODES / 64, 256, 0, stream>>>(W2, b2, g2, bt2, rm2, rv2);

    // layer 3
    k_agg_csr<<<(N_NODES * 32) / 256, 256, 0, stream>>>();
    k_gemm_bn_relu<false><<<N_NODES / 64, 256, 0, stream>>>(W3, b3, g3, bt3, rm3, rv3);

    // segment-mean pool + head MLP
    k_pool_seg<<<(N_GRAPHS * 32) / 256, 256, 0, stream>>>();
    k_head1<<<(N_GRAPHS * 64) / 256, 256, 0, stream>>>(Wc1, bc1);
    k_head2<<<(N_GRAPHS + 255) / 256, 256, 0, stream>>>(Wc2, bc2, outp);
}

// Round 7
// 2800.781 us; speedup vs baseline: 7.7761x; 1.0429x over previous
//
#include <hip/hip_runtime.h>
#include <hip/hip_fp16.h>

#define N_NODES 1000000
#define N_EDGES 4000000
#define N_GRAPHS 32768
#define BN_EPS 1e-5f
#define NBLK1 3907   // ceil(N_NODES/256)

// ---------------------------------------------------------------------------
// Static device-global scratch (ws_size too small for the intermediates).
// fp16 ping-pong feature buffers keep the edge-gather set L3-resident;
// all arithmetic is f32 (fp16 is storage-only).
// NOTE: device globals must ONLY be referenced from device code — passing
// them as kernel launch arguments from host passes the host shadow address
// (round-6 fault). Ping-pong direction is a template parameter instead.
// ---------------------------------------------------------------------------
__device__ __half g_hA[128000000];      // 256 MB node features
__device__ __half g_hB[128000000];      // 256 MB node features (aliased as f32 px in layer 1)
__device__ float  g_agg7[7000000];      //  28 MB layer-1 agg; later pooled+hidden
__device__ float  g_dinv[N_NODES];
__device__ int    g_rowcnt[N_NODES];
__device__ int    g_row_start[N_NODES + 1];
__device__ int    g_csr_src[N_EDGES];
__device__ int    g_part[NBLK1];
__device__ int    g_gstart[N_GRAPHS + 1];

#define HIDDEN_OFF 4259840   // pooled = g_agg7[0..4194304); hidden after pad

// ---------------- fp16 helpers (16 B = 8 halfs per lane) ----------------

__device__ __forceinline__ void set8(uint4 raw, float f[8]) {
    __half2 h; float2 a;
    __builtin_memcpy(&h, &raw.x, 4); a = __half22float2(h); f[0] = a.x; f[1] = a.y;
    __builtin_memcpy(&h, &raw.y, 4); a = __half22float2(h); f[2] = a.x; f[3] = a.y;
    __builtin_memcpy(&h, &raw.z, 4); a = __half22float2(h); f[4] = a.x; f[5] = a.y;
    __builtin_memcpy(&h, &raw.w, 4); a = __half22float2(h); f[6] = a.x; f[7] = a.y;
}
__device__ __forceinline__ void add8(uint4 raw, float f[8]) {
    __half2 h; float2 a;
    __builtin_memcpy(&h, &raw.x, 4); a = __half22float2(h); f[0] += a.x; f[1] += a.y;
    __builtin_memcpy(&h, &raw.y, 4); a = __half22float2(h); f[2] += a.x; f[3] += a.y;
    __builtin_memcpy(&h, &raw.z, 4); a = __half22float2(h); f[4] += a.x; f[5] += a.y;
    __builtin_memcpy(&h, &raw.w, 4); a = __half22float2(h); f[6] += a.x; f[7] += a.y;
}
__device__ __forceinline__ void st_h4(__half* p, float4 v) {
    __half2 h01 = __floats2half2_rn(v.x, v.y);
    __half2 h23 = __floats2half2_rn(v.z, v.w);
    uint2 raw;
    __builtin_memcpy(&raw.x, &h01, 4);
    __builtin_memcpy(&raw.y, &h23, 4);
    __builtin_memcpy(p, &raw, 8);
}

// ---------------- CSR build ----------------

__global__ __launch_bounds__(256) void k_zero_cnt() {
    int i = blockIdx.x * 256 + threadIdx.x;
    if (i < N_NODES) g_rowcnt[i] = 0;
}

__global__ __launch_bounds__(256) void k_hist(const int* __restrict__ dst) {
    int e = blockIdx.x * 256 + threadIdx.x;
    if (e < N_EDGES) atomicAdd(&g_rowcnt[dst[e]], 1);
}

__global__ __launch_bounds__(256) void k_dinv() {
    int i = blockIdx.x * 256 + threadIdx.x;
    if (i < N_NODES) g_dinv[i] = rsqrtf((float)(1 + g_rowcnt[i]));
}

__global__ __launch_bounds__(256) void k_scan1() {
    __shared__ int sh[256];
    int i = blockIdx.x * 256 + threadIdx.x;
    int v = (i < N_NODES) ? g_rowcnt[i] : 0;
    sh[threadIdx.x] = v;
    __syncthreads();
#pragma unroll
    for (int off = 1; off < 256; off <<= 1) {
        int t = (threadIdx.x >= off) ? sh[threadIdx.x - off] : 0;
        __syncthreads();
        sh[threadIdx.x] += t;
        __syncthreads();
    }
    int incl = sh[threadIdx.x];
    if (i < N_NODES) g_row_start[i] = incl - v;
    if (threadIdx.x == 255) g_part[blockIdx.x] = incl;
}

__global__ __launch_bounds__(256) void k_scan2() {
    __shared__ int sh[256];
    int base = threadIdx.x * 16;
    int local[16];
    int s = 0;
#pragma unroll
    for (int k = 0; k < 16; ++k) {
        local[k] = (base + k < NBLK1) ? g_part[base + k] : 0;
        s += local[k];
    }
    sh[threadIdx.x] = s;
    __syncthreads();
#pragma unroll
    for (int off = 1; off < 256; off <<= 1) {
        int t = (threadIdx.x >= off) ? sh[threadIdx.x - off] : 0;
        __syncthreads();
        sh[threadIdx.x] += t;
        __syncthreads();
    }
    int carry = sh[threadIdx.x] - s;
#pragma unroll
    for (int k = 0; k < 16; ++k) {
        if (base + k < NBLK1) {
            int t = local[k];
            g_part[base + k] = carry;
            carry += t;
        }
    }
}

__global__ __launch_bounds__(256) void k_scan3() {
    int i = blockIdx.x * 256 + threadIdx.x;
    if (i < N_NODES) {
        g_row_start[i] += g_part[blockIdx.x];
        g_rowcnt[i] = 0;
    }
    if (i == 0) g_row_start[N_NODES] = N_EDGES;
}

__global__ __launch_bounds__(256) void k_scatter(const int* __restrict__ src,
                                                 const int* __restrict__ dst) {
    int e = blockIdx.x * 256 + threadIdx.x;
    if (e >= N_EDGES) return;
    int d = dst[e];
    int pos = g_row_start[d] + atomicAdd(&g_rowcnt[d], 1);
    g_csr_src[pos] = src[e];
}

// ---------------- layer 1 ----------------

// px[i] = dinv[i]*x[i]  (px aliases g_hB as f32; dead once layer 2 runs)
__global__ __launch_bounds__(256) void k_p7(const float* __restrict__ x) {
    int i = blockIdx.x * 256 + threadIdx.x;
    if (i >= N_NODES) return;
    float w = g_dinv[i];
    float* px = (float*)g_hB;
#pragma unroll
    for (int k = 0; k < 7; ++k) px[i * 7 + k] = x[i * 7 + k] * w;
}

// agg7[d] = px[d] + sum px[s], 8 lanes/node, 4-deep MLP
__global__ __launch_bounds__(256) void k_agg7_csr() {
    int t = blockIdx.x * 256 + threadIdx.x;
    int i = t >> 3;
    int c = t & 7;
    if (i >= N_NODES || c >= 7) return;
    const float* px = (const float*)g_hB;
    float acc = px[i * 7 + c];
    int e = g_row_start[i], e1 = g_row_start[i + 1];
    for (; e + 4 <= e1; e += 4) {
        int s0 = g_csr_src[e + 0], s1 = g_csr_src[e + 1];
        int s2 = g_csr_src[e + 2], s3 = g_csr_src[e + 3];
        float v0 = px[s0 * 7 + c], v1 = px[s1 * 7 + c];
        float v2 = px[s2 * 7 + c], v3 = px[s3 * 7 + c];
        acc += (v0 + v1) + (v2 + v3);
    }
    for (; e < e1; ++e) acc += px[g_csr_src[e] * 7 + c];
    g_agg7[i * 7 + c] = acc;
}

// h1 = relu(bn(dinv*(agg7.W1) + b)); store q1 = dinv*h1 (fp16, half2 stores)
__global__ __launch_bounds__(256) void k_lin1_bn_relu(const float* __restrict__ W,
                                                      const float* __restrict__ b,
                                                      const float* __restrict__ g,
                                                      const float* __restrict__ bt,
                                                      const float* __restrict__ rm,
                                                      const float* __restrict__ rv) {
    int t = blockIdx.x * 256 + threadIdx.x;   // node*64 + cpair
    int i = t >> 6, c = (t & 63) * 2;
    if (i >= N_NODES) return;
    float a[7];
#pragma unroll
    for (int k = 0; k < 7; ++k) a[k] = g_agg7[i * 7 + k];
    float z0 = 0.f, z1 = 0.f;
#pragma unroll
    for (int k = 0; k < 7; ++k) {
        z0 = fmaf(a[k], W[k * 128 + c], z0);
        z1 = fmaf(a[k], W[k * 128 + c + 1], z1);
    }
    float dv = g_dinv[i];
    z0 *= dv; z1 *= dv;
    float s0 = g[c] * rsqrtf(rv[c] + BN_EPS);
    float s1 = g[c + 1] * rsqrtf(rv[c + 1] + BN_EPS);
    float o0 = fmaf(b[c] - rm[c], s0, bt[c]);
    float o1 = fmaf(b[c + 1] - rm[c + 1], s1, bt[c + 1]);
    float h0 = fmaxf(fmaf(z0, s0, o0), 0.f) * dv;
    float h1 = fmaxf(fmaf(z1, s1, o1), 0.f) * dv;
    __half2 out = __floats2half2_rn(h0, h1);
    *(__half2*)(g_hA + (size_t)i * 128 + c) = out;
}

// ---------------- fused CSR-gather + 128x128 GEMM + BN + ReLU ---------------
// 64 nodes/block. Gather: 16 lanes/node x 8ch (16B fp16 loads), 4-deep MLP,
// f32 accumulate into LDS A-tile. GEMM: fp32 register-blocked (TM=4,TN=8).
// ATOB: true = read g_hA, write g_hB; false = the reverse. (Globals referenced
// in device code only — see note at top.)

template <bool PRE, bool ATOB>
__global__ __launch_bounds__(256) void k_agg_gemm(const float* __restrict__ W,
                                                  const float* __restrict__ b,
                                                  const float* __restrict__ g,
                                                  const float* __restrict__ bt,
                                                  const float* __restrict__ rm,
                                                  const float* __restrict__ rv) {
    const __half* __restrict__ hin  = ATOB ? g_hA : g_hB;
    __half* __restrict__       hout = ATOB ? g_hB : g_hA;

    __shared__ float As[64][132];
    __shared__ float Ws[32][128];
    const int tid = threadIdx.x;
    const int node0 = blockIdx.x * 64;
    const int slot = tid >> 4;          // 0..15
    const int c0 = (tid & 15) * 8;      // channel group (8 halfs = 16 B)

    // ---- gather phase: A[row] = q[i] + sum_{s in N(i)} q[s]  (f32) ----
#pragma unroll
    for (int pass = 0; pass < 4; ++pass) {
        int i = node0 + pass * 16 + slot;
        float f[8];
        set8(*(const uint4*)(hin + (size_t)i * 128 + c0), f);   // self term
        int e = g_row_start[i], e1 = g_row_start[i + 1];
        for (; e + 4 <= e1; e += 4) {
            int s0 = g_csr_src[e + 0], s1 = g_csr_src[e + 1];
            int s2 = g_csr_src[e + 2], s3 = g_csr_src[e + 3];
            uint4 r0 = *(const uint4*)(hin + (size_t)s0 * 128 + c0);
            uint4 r1 = *(const uint4*)(hin + (size_t)s1 * 128 + c0);
            uint4 r2 = *(const uint4*)(hin + (size_t)s2 * 128 + c0);
            uint4 r3 = *(const uint4*)(hin + (size_t)s3 * 128 + c0);
            add8(r0, f); add8(r1, f); add8(r2, f); add8(r3, f);
        }
        for (; e < e1; ++e) {
            int s = g_csr_src[e];
            add8(*(const uint4*)(hin + (size_t)s * 128 + c0), f);
        }
        int row = pass * 16 + slot;
        *(float4*)(&As[row][c0])     = make_float4(f[0], f[1], f[2], f[3]);
        *(float4*)(&As[row][c0 + 4]) = make_float4(f[4], f[5], f[6], f[7]);
    }

    // ---- GEMM phase ----
    float acc[4][8];
#pragma unroll
    for (int r = 0; r < 4; ++r)
#pragma unroll
        for (int j = 0; j < 8; ++j) acc[r][j] = 0.f;

    const int tr = tid >> 4;
    const int tc = tid & 15;

    for (int kb = 0; kb < 4; ++kb) {
        __syncthreads();                 // kb=0: makes As visible too
#pragma unroll
        for (int i = 0; i < 4; ++i) {
            int t = tid + i * 256;
            int r = t >> 5, k4 = (t & 31) << 2;
            *(float4*)(&Ws[r][k4]) = *(const float4*)(W + (size_t)(kb * 32 + r) * 128 + k4);
        }
        __syncthreads();
#pragma unroll
        for (int k = 0; k < 32; ++k) {
            float a[4];
#pragma unroll
            for (int r = 0; r < 4; ++r) a[r] = As[tr * 4 + r][kb * 32 + k];
            float4 w0 = *(const float4*)(&Ws[k][tc * 4]);
            float4 w1 = *(const float4*)(&Ws[k][64 + tc * 4]);
            float w[8] = {w0.x, w0.y, w0.z, w0.w, w1.x, w1.y, w1.z, w1.w};
#pragma unroll
            for (int r = 0; r < 4; ++r)
#pragma unroll
                for (int j = 0; j < 8; ++j)
                    acc[r][j] = fmaf(a[r], w[j], acc[r][j]);
        }
    }

    float4 dv4 = *(const float4*)(g_dinv + node0 + tr * 4);
    float dv[4] = {dv4.x, dv4.y, dv4.z, dv4.w};

#pragma unroll
    for (int half = 0; half < 2; ++half) {
        int cb = half * 64 + tc * 4;
        float s0 = g[cb + 0] * rsqrtf(rv[cb + 0] + BN_EPS);
        float s1 = g[cb + 1] * rsqrtf(rv[cb + 1] + BN_EPS);
        float s2 = g[cb + 2] * rsqrtf(rv[cb + 2] + BN_EPS);
        float s3 = g[cb + 3] * rsqrtf(rv[cb + 3] + BN_EPS);
        float o0 = fmaf(b[cb + 0] - rm[cb + 0], s0, bt[cb + 0]);
        float o1 = fmaf(b[cb + 1] - rm[cb + 1], s1, bt[cb + 1]);
        float o2 = fmaf(b[cb + 2] - rm[cb + 2], s2, bt[cb + 2]);
        float o3 = fmaf(b[cb + 3] - rm[cb + 3], s3, bt[cb + 3]);
#pragma unroll
        for (int r = 0; r < 4; ++r) {
            float pm = PRE ? dv[r] : 1.0f;
            float4 o;
            o.x = fmaxf(fmaf(acc[r][half * 4 + 0] * dv[r], s0, o0), 0.f) * pm;
            o.y = fmaxf(fmaf(acc[r][half * 4 + 1] * dv[r], s1, o1), 0.f) * pm;
            o.z = fmaxf(fmaf(acc[r][half * 4 + 2] * dv[r], s2, o2), 0.f) * pm;
            o.w = fmaxf(fmaf(acc[r][half * 4 + 3] * dv[r], s3, o3), 0.f) * pm;
            st_h4(hout + (size_t)(node0 + tr * 4 + r) * 128 + cb, o);
        }
    }
}

// ---------------- pooling + head ----------------

__global__ __launch_bounds__(256) void k_gstart(const int* __restrict__ batch) {
    int gidx = blockIdx.x * 256 + threadIdx.x;
    if (gidx > N_GRAPHS) return;
    int lo = 0, hi = N_NODES;
    while (lo < hi) {
        int mid = (lo + hi) >> 1;
        if (batch[mid] < gidx) lo = mid + 1; else hi = mid;
    }
    g_gstart[gidx] = lo;
}

__global__ __launch_bounds__(256) void k_pool_seg() {
    int t = blockIdx.x * 256 + threadIdx.x;
    int gi = t >> 4;
    if (gi >= N_GRAPHS) return;
    int c0 = (t & 15) * 8;
    int s0 = g_gstart[gi], s1 = g_gstart[gi + 1];
    float f[8] = {0.f, 0.f, 0.f, 0.f, 0.f, 0.f, 0.f, 0.f};
    for (int i = s0; i < s1; ++i)
        add8(*(const uint4*)(g_hA + (size_t)i * 128 + c0), f);
    float inv = 1.0f / (float)max(s1 - s0, 1);
    float* pooled = g_agg7;
    *(float4*)(pooled + (size_t)gi * 128 + c0)     = make_float4(f[0]*inv, f[1]*inv, f[2]*inv, f[3]*inv);
    *(float4*)(pooled + (size_t)gi * 128 + c0 + 4) = make_float4(f[4]*inv, f[5]*inv, f[6]*inv, f[7]*inv);
}

__global__ __launch_bounds__(256) void k_head1(const float* __restrict__ Wc1,
                                               const float* __restrict__ bc1) {
    int t = blockIdx.x * 256 + threadIdx.x;
    int gi = t >> 6, c = t & 63;
    if (gi >= N_GRAPHS) return;
    const float* pooled = g_agg7;
    float* hidden = g_agg7 + HIDDEN_OFF;
    float z = 0.f;
#pragma unroll 8
    for (int k = 0; k < 128; ++k) z = fmaf(pooled[gi * 128 + k], Wc1[k * 64 + c], z);
    hidden[t] = fmaxf(z + bc1[c], 0.f);
}

__global__ __launch_bounds__(256) void k_head2(const float* __restrict__ Wc2,
                                               const float* __restrict__ bc2,
                                               float* __restrict__ out) {
    int gi = blockIdx.x * 256 + threadIdx.x;
    if (gi >= N_GRAPHS) return;
    const float* hidden = g_agg7 + HIDDEN_OFF;
    float z = bc2[0];
#pragma unroll 8
    for (int k = 0; k < 64; ++k) z = fmaf(hidden[gi * 64 + k], Wc2[k], z);
    out[gi] = z;
}

// ---------------- launch ----------------

extern "C" void kernel_launch(void* const* d_in, const int* in_sizes, int n_in,
                              void* d_out, int out_size, void* d_ws, size_t ws_size,
                              hipStream_t stream) {
    const float* x     = (const float*)d_in[0];
    const int*   ei    = (const int*)d_in[1];
    const int*   batch = (const int*)d_in[2];
    const float* W1 = (const float*)d_in[3];
    const float* b1 = (const float*)d_in[4];
    const float* g1 = (const float*)d_in[5];
    const float* bt1= (const float*)d_in[6];
    const float* rm1= (const float*)d_in[7];
    const float* rv1= (const float*)d_in[8];
    const float* W2 = (const float*)d_in[9];
    const float* b2 = (const float*)d_in[10];
    const float* g2 = (const float*)d_in[11];
    const float* bt2= (const float*)d_in[12];
    const float* rm2= (const float*)d_in[13];
    const float* rv2= (const float*)d_in[14];
    const float* W3 = (const float*)d_in[15];
    const float* b3 = (const float*)d_in[16];
    const float* g3 = (const float*)d_in[17];
    const float* bt3= (const float*)d_in[18];
    const float* rm3= (const float*)d_in[19];
    const float* rv3= (const float*)d_in[20];
    const float* Wc1= (const float*)d_in[21];
    const float* bc1= (const float*)d_in[22];
    const float* Wc2= (const float*)d_in[23];
    const float* bc2= (const float*)d_in[24];
    float* outp = (float*)d_out;
    (void)d_ws; (void)ws_size; (void)n_in; (void)in_sizes;

    const int* srcp = ei;
    const int* dstp = ei + N_EDGES;

    // CSR build (by dst) + dinv
    k_zero_cnt<<<NBLK1, 256, 0, stream>>>();
    k_hist<<<(N_EDGES + 255) / 256, 256, 0, stream>>>(dstp);
    k_dinv<<<NBLK1, 256, 0, stream>>>();
    k_scan1<<<NBLK1, 256, 0, stream>>>();
    k_scan2<<<1, 256, 0, stream>>>();
    k_scan3<<<NBLK1, 256, 0, stream>>>();
    k_scatter<<<(N_EDGES + 255) / 256, 256, 0, stream>>>(srcp, dstp);

    // graph boundaries for pooling
    k_gstart<<<(N_GRAPHS + 1 + 255) / 256, 256, 0, stream>>>(batch);

    // layer 1: premultiply -> gather -> linear+BN+ReLU
    k_p7<<<(N_NODES + 255) / 256, 256, 0, stream>>>(x);
    k_agg7_csr<<<(N_NODES * 8) / 256, 256, 0, stream>>>();
    k_lin1_bn_relu<<<(N_NODES * 64) / 256, 256, 0, stream>>>(W1, b1, g1, bt1, rm1, rv1);

    // layers 2,3: fused gather+GEMM, ping-pong hA <-> hB (direction via template)
    k_agg_gemm<true, true><<<N_NODES / 64, 256, 0, stream>>>(W2, b2, g2, bt2, rm2, rv2);
    k_agg_gemm<false, false><<<N_NODES / 64, 256, 0, stream>>>(W3, b3, g3, bt3, rm3, rv3);

    // segment-mean pool + head MLP
    k_pool_seg<<<(N_GRAPHS * 16) / 256, 256, 0, stream>>>();
    k_head1<<<(N_GRAPHS * 64) / 256, 256, 0, stream>>>(Wc1, bc1);
    k_head2<<<(N_GRAPHS + 255) / 256, 256, 0, stream>>>(Wc2, bc2, outp);
}

// Round 9
// 2195.163 us; speedup vs baseline: 9.9214x; 1.2759x over previous
//
#include <hip/hip_runtime.h>
#include <hip/hip_fp16.h>

#define N_NODES 1000000
#define N_EDGES 4000000
#define N_GRAPHS 32768
#define BN_EPS 1e-5f
#define NBLK1 3907   // ceil(N_NODES/256)

// ---------------------------------------------------------------------------
// Static device-global scratch (ws_size too small for the intermediates).
// fp16 ping-pong feature buffers keep the edge-gather set L3-resident;
// arithmetic is f32 (fp16 is storage-only).
// NOTE: device globals must ONLY be referenced from device code — host-side
// references pass the host shadow address (round-6 fault). Ping-pong
// direction is a template parameter.
// ---------------------------------------------------------------------------
__device__ __half g_hA[128000000];      // 256 MB node features
__device__ __half g_hB[128000000];      // 256 MB node features (aliased as f32 px in layer 1)
__device__ float  g_agg7[7000000];      //  28 MB layer-1 agg; later pooled+hidden
__device__ float  g_dinv[N_NODES];
__device__ int    g_rowcnt[N_NODES];
__device__ int    g_row_start[N_NODES + 1];
__device__ int    g_csr_src[N_EDGES];
__device__ int    g_part[NBLK1];
__device__ int    g_gstart[N_GRAPHS + 1];

#define HIDDEN_OFF 4259840   // pooled = g_agg7[0..4194304); hidden after pad

// ---------------- fp16 helpers (16 B = 8 halfs per lane) ----------------

__device__ __forceinline__ void set8(uint4 raw, float f[8]) {
    __half2 h; float2 a;
    __builtin_memcpy(&h, &raw.x, 4); a = __half22float2(h); f[0] = a.x; f[1] = a.y;
    __builtin_memcpy(&h, &raw.y, 4); a = __half22float2(h); f[2] = a.x; f[3] = a.y;
    __builtin_memcpy(&h, &raw.z, 4); a = __half22float2(h); f[4] = a.x; f[5] = a.y;
    __builtin_memcpy(&h, &raw.w, 4); a = __half22float2(h); f[6] = a.x; f[7] = a.y;
}
__device__ __forceinline__ void add8(uint4 raw, float f[8]) {
    __half2 h; float2 a;
    __builtin_memcpy(&h, &raw.x, 4); a = __half22float2(h); f[0] += a.x; f[1] += a.y;
    __builtin_memcpy(&h, &raw.y, 4); a = __half22float2(h); f[2] += a.x; f[3] += a.y;
    __builtin_memcpy(&h, &raw.z, 4); a = __half22float2(h); f[4] += a.x; f[5] += a.y;
    __builtin_memcpy(&h, &raw.w, 4); a = __half22float2(h); f[6] += a.x; f[7] += a.y;
}
__device__ __forceinline__ uint4 pack8(const float f[8]) {
    __half2 h0 = __floats2half2_rn(f[0], f[1]);
    __half2 h1 = __floats2half2_rn(f[2], f[3]);
    __half2 h2 = __floats2half2_rn(f[4], f[5]);
    __half2 h3 = __floats2half2_rn(f[6], f[7]);
    uint4 raw;
    __builtin_memcpy(&raw.x, &h0, 4);
    __builtin_memcpy(&raw.y, &h1, 4);
    __builtin_memcpy(&raw.z, &h2, 4);
    __builtin_memcpy(&raw.w, &h3, 4);
    return raw;
}
__device__ __forceinline__ void st_h4(__half* p, float4 v) {
    __half2 h01 = __floats2half2_rn(v.x, v.y);
    __half2 h23 = __floats2half2_rn(v.z, v.w);
    uint2 raw;
    __builtin_memcpy(&raw.x, &h01, 4);
    __builtin_memcpy(&raw.y, &h23, 4);
    __builtin_memcpy(p, &raw, 8);
}

// ---------------- CSR build ----------------

__global__ __launch_bounds__(256) void k_zero_cnt() {
    int i = blockIdx.x * 256 + threadIdx.x;
    if (i < N_NODES) g_rowcnt[i] = 0;
}

__global__ __launch_bounds__(256) void k_hist(const int* __restrict__ dst) {
    int e = blockIdx.x * 256 + threadIdx.x;
    if (e < N_EDGES) atomicAdd(&g_rowcnt[dst[e]], 1);
}

__global__ __launch_bounds__(256) void k_dinv() {
    int i = blockIdx.x * 256 + threadIdx.x;
    if (i < N_NODES) g_dinv[i] = rsqrtf((float)(1 + g_rowcnt[i]));
}

__global__ __launch_bounds__(256) void k_scan1() {
    __shared__ int sh[256];
    int i = blockIdx.x * 256 + threadIdx.x;
    int v = (i < N_NODES) ? g_rowcnt[i] : 0;
    sh[threadIdx.x] = v;
    __syncthreads();
#pragma unroll
    for (int off = 1; off < 256; off <<= 1) {
        int t = (threadIdx.x >= off) ? sh[threadIdx.x - off] : 0;
        __syncthreads();
        sh[threadIdx.x] += t;
        __syncthreads();
    }
    int incl = sh[threadIdx.x];
    if (i < N_NODES) g_row_start[i] = incl - v;
    if (threadIdx.x == 255) g_part[blockIdx.x] = incl;
}

__global__ __launch_bounds__(256) void k_scan2() {
    __shared__ int sh[256];
    int base = threadIdx.x * 16;
    int local[16];
    int s = 0;
#pragma unroll
    for (int k = 0; k < 16; ++k) {
        local[k] = (base + k < NBLK1) ? g_part[base + k] : 0;
        s += local[k];
    }
    sh[threadIdx.x] = s;
    __syncthreads();
#pragma unroll
    for (int off = 1; off < 256; off <<= 1) {
        int t = (threadIdx.x >= off) ? sh[threadIdx.x - off] : 0;
        __syncthreads();
        sh[threadIdx.x] += t;
        __syncthreads();
    }
    int carry = sh[threadIdx.x] - s;
#pragma unroll
    for (int k = 0; k < 16; ++k) {
        if (base + k < NBLK1) {
            int t = local[k];
            g_part[base + k] = carry;
            carry += t;
        }
    }
}

__global__ __launch_bounds__(256) void k_scan3() {
    int i = blockIdx.x * 256 + threadIdx.x;
    if (i < N_NODES) {
        g_row_start[i] += g_part[blockIdx.x];
        g_rowcnt[i] = 0;
    }
    if (i == 0) g_row_start[N_NODES] = N_EDGES;
}

__global__ __launch_bounds__(256) void k_scatter(const int* __restrict__ src,
                                                 const int* __restrict__ dst) {
    int e = blockIdx.x * 256 + threadIdx.x;
    if (e >= N_EDGES) return;
    int d = dst[e];
    int pos = g_row_start[d] + atomicAdd(&g_rowcnt[d], 1);
    g_csr_src[pos] = src[e];
}

// ---------------- layer 1 ----------------

// px[i] = dinv[i]*x[i]  (px aliases g_hB as f32; dead once layer 2 runs)
__global__ __launch_bounds__(256) void k_p7(const float* __restrict__ x) {
    int i = blockIdx.x * 256 + threadIdx.x;
    if (i >= N_NODES) return;
    float w = g_dinv[i];
    float* px = (float*)g_hB;
#pragma unroll
    for (int k = 0; k < 7; ++k) px[i * 7 + k] = x[i * 7 + k] * w;
}

// agg7[d] = px[d] + sum px[s], 8 lanes/node, 4-deep MLP
__global__ __launch_bounds__(256) void k_agg7_csr() {
    int t = blockIdx.x * 256 + threadIdx.x;
    int i = t >> 3;
    int c = t & 7;
    if (i >= N_NODES || c >= 7) return;
    const float* px = (const float*)g_hB;
    float acc = px[i * 7 + c];
    int e = g_row_start[i], e1 = g_row_start[i + 1];
    for (; e + 4 <= e1; e += 4) {
        int s0 = g_csr_src[e + 0], s1 = g_csr_src[e + 1];
        int s2 = g_csr_src[e + 2], s3 = g_csr_src[e + 3];
        float v0 = px[s0 * 7 + c], v1 = px[s1 * 7 + c];
        float v2 = px[s2 * 7 + c], v3 = px[s3 * 7 + c];
        acc += (v0 + v1) + (v2 + v3);
    }
    for (; e < e1; ++e) acc += px[g_csr_src[e] * 7 + c];
    g_agg7[i * 7 + c] = acc;
}

// h1 = relu(bn(dinv*(agg7.W1) + b)); store q1 = dinv*h1 (fp16, half2 stores)
__global__ __launch_bounds__(256) void k_lin1_bn_relu(const float* __restrict__ W,
                                                      const float* __restrict__ b,
                                                      const float* __restrict__ g,
                                                      const float* __restrict__ bt,
                                                      const float* __restrict__ rm,
                                                      const float* __restrict__ rv) {
    int t = blockIdx.x * 256 + threadIdx.x;   // node*64 + cpair
    int i = t >> 6, c = (t & 63) * 2;
    if (i >= N_NODES) return;
    float a[7];
#pragma unroll
    for (int k = 0; k < 7; ++k) a[k] = g_agg7[i * 7 + k];
    float z0 = 0.f, z1 = 0.f;
#pragma unroll
    for (int k = 0; k < 7; ++k) {
        z0 = fmaf(a[k], W[k * 128 + c], z0);
        z1 = fmaf(a[k], W[k * 128 + c + 1], z1);
    }
    float dv = g_dinv[i];
    z0 *= dv; z1 *= dv;
    float s0 = g[c] * rsqrtf(rv[c] + BN_EPS);
    float s1 = g[c + 1] * rsqrtf(rv[c + 1] + BN_EPS);
    float o0 = fmaf(b[c] - rm[c], s0, bt[c]);
    float o1 = fmaf(b[c + 1] - rm[c + 1], s1, bt[c + 1]);
    float h0 = fmaxf(fmaf(z0, s0, o0), 0.f) * dv;
    float h1 = fmaxf(fmaf(z1, s1, o1), 0.f) * dv;
    __half2 out = __floats2half2_rn(h0, h1);
    *(__half2*)(g_hA + (size_t)i * 128 + c) = out;
}

// ---------------- fused CSR-gather + 128x128 GEMM + BN + ReLU ---------------
// 64 nodes/block. Gather: 16 lanes/node x 8ch (16B fp16 loads), 4-deep MLP,
// f32 accumulate -> fp16 LDS A-tile (144-half row pad: store pattern 2-way/free).
// GEMM: fp32 FMA, A read as half2 k-pairs, W staged in 16-row f32 chunks.
// LDS = 64*144*2 + 16*128*4 = 26,624 B -> ~5-6 blocks/CU (vs 3 at 50 KB).

template <bool PRE, bool ATOB>
__global__ __launch_bounds__(256) void k_agg_gemm(const float* __restrict__ W,
                                                  const float* __restrict__ b,
                                                  const float* __restrict__ g,
                                                  const float* __restrict__ bt,
                                                  const float* __restrict__ rm,
                                                  const float* __restrict__ rv) {
    const __half* __restrict__ hin  = ATOB ? g_hA : g_hB;
    __half* __restrict__       hout = ATOB ? g_hB : g_hA;

    __shared__ __half As[64][144];
    __shared__ float  Ws[16][128];
    const int tid = threadIdx.x;
    const int node0 = blockIdx.x * 64;
    const int slot = tid >> 4;          // 0..15
    const int c0 = (tid & 15) * 8;      // channel group (8 halfs = 16 B)

    // ---- gather phase: A[row] = q[i] + sum_{s in N(i)} q[s]  (f32 acc) ----
#pragma unroll
    for (int pass = 0; pass < 4; ++pass) {
        int i = node0 + pass * 16 + slot;
        float f[8];
        set8(*(const uint4*)(hin + (size_t)i * 128 + c0), f);   // self term
        int e = g_row_start[i], e1 = g_row_start[i + 1];
        for (; e + 4 <= e1; e += 4) {
            int s0 = g_csr_src[e + 0], s1 = g_csr_src[e + 1];
            int s2 = g_csr_src[e + 2], s3 = g_csr_src[e + 3];
            uint4 r0 = *(const uint4*)(hin + (size_t)s0 * 128 + c0);
            uint4 r1 = *(const uint4*)(hin + (size_t)s1 * 128 + c0);
            uint4 r2 = *(const uint4*)(hin + (size_t)s2 * 128 + c0);
            uint4 r3 = *(const uint4*)(hin + (size_t)s3 * 128 + c0);
            add8(r0, f); add8(r1, f); add8(r2, f); add8(r3, f);
        }
        for (; e < e1; ++e) {
            int s = g_csr_src[e];
            add8(*(const uint4*)(hin + (size_t)s * 128 + c0), f);
        }
        int row = pass * 16 + slot;
        *(uint4*)(&As[row][c0]) = pack8(f);
    }

    // ---- GEMM phase ----
    float acc[4][8];
#pragma unroll
    for (int r = 0; r < 4; ++r)
#pragma unroll
        for (int j = 0; j < 8; ++j) acc[r][j] = 0.f;

    const int tr = tid >> 4;
    const int tc = tid & 15;

    for (int kb = 0; kb < 8; ++kb) {
        __syncthreads();                 // kb=0: makes As visible too
#pragma unroll
        for (int i2 = 0; i2 < 2; ++i2) {
            int t = tid + i2 * 256;
            int r = t >> 5, k4 = (t & 31) << 2;
            *(float4*)(&Ws[r][k4]) = *(const float4*)(W + (size_t)(kb * 16 + r) * 128 + k4);
        }
        __syncthreads();
#pragma unroll
        for (int kk = 0; kk < 8; ++kk) {
            int kg = kb * 16 + kk * 2;   // global k (even)
            float a0[4], a1[4];
#pragma unroll
            for (int r = 0; r < 4; ++r) {
                __half2 h = *(const __half2*)(&As[tr * 4 + r][kg]);
                float2 af = __half22float2(h);
                a0[r] = af.x; a1[r] = af.y;
            }
            float4 w00 = *(const float4*)(&Ws[kk * 2][tc * 4]);
            float4 w01 = *(const float4*)(&Ws[kk * 2][64 + tc * 4]);
            float4 w10 = *(const float4*)(&Ws[kk * 2 + 1][tc * 4]);
            float4 w11 = *(const float4*)(&Ws[kk * 2 + 1][64 + tc * 4]);
            float w0[8] = {w00.x, w00.y, w00.z, w00.w, w01.x, w01.y, w01.z, w01.w};
            float w1[8] = {w10.x, w10.y, w10.z, w10.w, w11.x, w11.y, w11.z, w11.w};
#pragma unroll
            for (int r = 0; r < 4; ++r)
#pragma unroll
                for (int j = 0; j < 8; ++j)
                    acc[r][j] = fmaf(a0[r], w0[j], fmaf(a1[r], w1[j], acc[r][j]));
        }
    }

    float4 dv4 = *(const float4*)(g_dinv + node0 + tr * 4);
    float dv[4] = {dv4.x, dv4.y, dv4.z, dv4.w};

#pragma unroll
    for (int half = 0; half < 2; ++half) {
        int cb = half * 64 + tc * 4;
        float s0 = g[cb + 0] * rsqrtf(rv[cb + 0] + BN_EPS);
        float s1 = g[cb + 1] * rsqrtf(rv[cb + 1] + BN_EPS);
        float s2 = g[cb + 2] * rsqrtf(rv[cb + 2] + BN_EPS);
        float s3 = g[cb + 3] * rsqrtf(rv[cb + 3] + BN_EPS);
        float o0 = fmaf(b[cb + 0] - rm[cb + 0], s0, bt[cb + 0]);
        float o1 = fmaf(b[cb + 1] - rm[cb + 1], s1, bt[cb + 1]);
        float o2 = fmaf(b[cb + 2] - rm[cb + 2], s2, bt[cb + 2]);
        float o3 = fmaf(b[cb + 3] - rm[cb + 3], s3, bt[cb + 3]);
#pragma unroll
        for (int r = 0; r < 4; ++r) {
            float pm = PRE ? dv[r] : 1.0f;
            float4 o;
            o.x = fmaxf(fmaf(acc[r][half * 4 + 0] * dv[r], s0, o0), 0.f) * pm;
            o.y = fmaxf(fmaf(acc[r][half * 4 + 1] * dv[r], s1, o1), 0.f) * pm;
            o.z = fmaxf(fmaf(acc[r][half * 4 + 2] * dv[r], s2, o2), 0.f) * pm;
            o.w = fmaxf(fmaf(acc[r][half * 4 + 3] * dv[r], s3, o3), 0.f) * pm;
            st_h4(hout + (size_t)(node0 + tr * 4 + r) * 128 + cb, o);
        }
    }
}

// ---------------- pooling + head ----------------

__global__ __launch_bounds__(256) void k_gstart(const int* __restrict__ batch) {
    int gidx = blockIdx.x * 256 + threadIdx.x;
    if (gidx > N_GRAPHS) return;
    int lo = 0, hi = N_NODES;
    while (lo < hi) {
        int mid = (lo + hi) >> 1;
        if (batch[mid] < gidx) lo = mid + 1; else hi = mid;
    }
    g_gstart[gidx] = lo;
}

__global__ __launch_bounds__(256) void k_pool_seg() {
    int t = blockIdx.x * 256 + threadIdx.x;
    int gi = t >> 4;
    if (gi >= N_GRAPHS) return;
    int c0 = (t & 15) * 8;
    int s0 = g_gstart[gi], s1 = g_gstart[gi + 1];
    float f[8] = {0.f, 0.f, 0.f, 0.f, 0.f, 0.f, 0.f, 0.f};
    for (int i = s0; i < s1; ++i)
        add8(*(const uint4*)(g_hA + (size_t)i * 128 + c0), f);
    float inv = 1.0f / (float)max(s1 - s0, 1);
    float* pooled = g_agg7;
    *(float4*)(pooled + (size_t)gi * 128 + c0)     = make_float4(f[0]*inv, f[1]*inv, f[2]*inv, f[3]*inv);
    *(float4*)(pooled + (size_t)gi * 128 + c0 + 4) = make_float4(f[4]*inv, f[5]*inv, f[6]*inv, f[7]*inv);
}

__global__ __launch_bounds__(256) void k_head1(const float* __restrict__ Wc1,
                                               const float* __restrict__ bc1) {
    int t = blockIdx.x * 256 + threadIdx.x;
    int gi = t >> 6, c = t & 63;
    if (gi >= N_GRAPHS) return;
    const float* pooled = g_agg7;
    float* hidden = g_agg7 + HIDDEN_OFF;
    float z = 0.f;
#pragma unroll 8
    for (int k = 0; k < 128; ++k) z = fmaf(pooled[gi * 128 + k], Wc1[k * 64 + c], z);
    hidden[t] = fmaxf(z + bc1[c], 0.f);
}

__global__ __launch_bounds__(256) void k_head2(const float* __restrict__ Wc2,
                                               const float* __restrict__ bc2,
                                               float* __restrict__ out) {
    int gi = blockIdx.x * 256 + threadIdx.x;
    if (gi >= N_GRAPHS) return;
    const float* hidden = g_agg7 + HIDDEN_OFF;
    float z = bc2[0];
#pragma unroll 8
    for (int k = 0; k < 64; ++k) z = fmaf(hidden[gi * 64 + k], Wc2[k], z);
    out[gi] = z;
}

// ---------------- launch ----------------

extern "C" void kernel_launch(void* const* d_in, const int* in_sizes, int n_in,
                              void* d_out, int out_size, void* d_ws, size_t ws_size,
                              hipStream_t stream) {
    const float* x     = (const float*)d_in[0];
    const int*   ei    = (const int*)d_in[1];
    const int*   batch = (const int*)d_in[2];
    const float* W1 = (const float*)d_in[3];
    const float* b1 = (const float*)d_in[4];
    const float* g1 = (const float*)d_in[5];
    const float* bt1= (const float*)d_in[6];
    const float* rm1= (const float*)d_in[7];
    const float* rv1= (const float*)d_in[8];
    const float* W2 = (const float*)d_in[9];
    const float* b2 = (const float*)d_in[10];
    const float* g2 = (const float*)d_in[11];
    const float* bt2= (const float*)d_in[12];
    const float* rm2= (const float*)d_in[13];
    const float* rv2= (const float*)d_in[14];
    const float* W3 = (const float*)d_in[15];
    const float* b3 = (const float*)d_in[16];
    const float* g3 = (const float*)d_in[17];
    const float* bt3= (const float*)d_in[18];
    const float* rm3= (const float*)d_in[19];
    const float* rv3= (const float*)d_in[20];
    const float* Wc1= (const float*)d_in[21];
    const float* bc1= (const float*)d_in[22];
    const float* Wc2= (const float*)d_in[23];
    const float* bc2= (const float*)d_in[24];
    float* outp = (float*)d_out;
    (void)d_ws; (void)ws_size; (void)n_in; (void)in_sizes;

    const int* srcp = ei;
    const int* dstp = ei + N_EDGES;

    // CSR build (by dst) + dinv
    k_zero_cnt<<<NBLK1, 256, 0, stream>>>();
    k_hist<<<(N_EDGES + 255) / 256, 256, 0, stream>>>(dstp);
    k_dinv<<<NBLK1, 256, 0, stream>>>();
    k_scan1<<<NBLK1, 256, 0, stream>>>();
    k_scan2<<<1, 256, 0, stream>>>();
    k_scan3<<<NBLK1, 256, 0, stream>>>();
    k_scatter<<<(N_EDGES + 255) / 256, 256, 0, stream>>>(srcp, dstp);

    // graph boundaries for pooling
    k_gstart<<<(N_GRAPHS + 1 + 255) / 256, 256, 0, stream>>>(batch);

    // layer 1: premultiply -> gather -> linear+BN+ReLU
    k_p7<<<(N_NODES + 255) / 256, 256, 0, stream>>>(x);
    k_agg7_csr<<<(N_NODES * 8) / 256, 256, 0, stream>>>();
    k_lin1_bn_relu<<<(N_NODES * 64) / 256, 256, 0, stream>>>(W1, b1, g1, bt1, rm1, rv1);

    // layers 2,3: fused gather+GEMM, ping-pong hA <-> hB (direction via template)
    k_agg_gemm<true, true><<<N_NODES / 64, 256, 0, stream>>>(W2, b2, g2, bt2, rm2, rv2);
    k_agg_gemm<false, false><<<N_NODES / 64, 256, 0, stream>>>(W3, b3, g3, bt3, rm3, rv3);

    // segment-mean pool + head MLP
    k_pool_seg<<<(N_GRAPHS * 16) / 256, 256, 0, stream>>>();
    k_head1<<<(N_GRAPHS * 64) / 256, 256, 0, stream>>>(Wc1, bc1);
    k_head2<<<(N_GRAPHS + 255) / 256, 256, 0, stream>>>(Wc2, bc2, outp);
}

// Round 15
// 2130.638 us; speedup vs baseline: 10.2218x; 1.0303x over previous
//
#include <hip/hip_runtime.h>
#include <hip/hip_fp16.h>

#define N_NODES 1000000
#define N_EDGES 4000000
#define N_GRAPHS 32768
#define BN_EPS 1e-5f
#define NBLK1 3907   // ceil(N_NODES/256)

typedef _Float16 f16;
typedef f16   f16x8 __attribute__((ext_vector_type(8)));
typedef float f32x4 __attribute__((ext_vector_type(4)));

// ---------------------------------------------------------------------------
// Static device-global scratch (ws_size too small for the intermediates).
// fp16 ping-pong feature buffers keep the edge-gather set L3-resident.
// NOTE: device globals must ONLY be referenced from device code (round-6
// fault: host-side refs pass the host shadow address). Buffer selection is
// via template parameters.
// ---------------------------------------------------------------------------
__device__ __half g_hA[128000000];      // 256 MB node features
__device__ __half g_hB[128000000];      // 256 MB node features (aliased as f32 px in layer 1)
__device__ float  g_agg7[7000000];      //  28 MB layer-1 agg; later pooled+hidden
__device__ float  g_dinv[N_NODES];
__device__ int    g_rowcnt[N_NODES];
__device__ int    g_row_start[N_NODES + 1];
__device__ int    g_csr_src[N_EDGES];
__device__ int    g_part[NBLK1];
__device__ int    g_gstart[N_GRAPHS + 1];
__device__ __align__(16) __half g_wt2[16384];   // W2^T fp16 [n][k]
__device__ __align__(16) __half g_wt3[16384];   // W3^T fp16 [n][k]

#define HIDDEN_OFF 4259840   // pooled = g_agg7[0..4194304); hidden after pad

// ---------------- fp16 helpers (16 B = 8 halfs per lane) ----------------

__device__ __forceinline__ void set8(uint4 raw, float f[8]) {
    __half2 h; float2 a;
    __builtin_memcpy(&h, &raw.x, 4); a = __half22float2(h); f[0] = a.x; f[1] = a.y;
    __builtin_memcpy(&h, &raw.y, 4); a = __half22float2(h); f[2] = a.x; f[3] = a.y;
    __builtin_memcpy(&h, &raw.z, 4); a = __half22float2(h); f[4] = a.x; f[5] = a.y;
    __builtin_memcpy(&h, &raw.w, 4); a = __half22float2(h); f[6] = a.x; f[7] = a.y;
}
__device__ __forceinline__ void add8(uint4 raw, float f[8]) {
    __half2 h; float2 a;
    __builtin_memcpy(&h, &raw.x, 4); a = __half22float2(h); f[0] += a.x; f[1] += a.y;
    __builtin_memcpy(&h, &raw.y, 4); a = __half22float2(h); f[2] += a.x; f[3] += a.y;
    __builtin_memcpy(&h, &raw.z, 4); a = __half22float2(h); f[4] += a.x; f[5] += a.y;
    __builtin_memcpy(&h, &raw.w, 4); a = __half22float2(h); f[6] += a.x; f[7] += a.y;
}
__device__ __forceinline__ uint4 pack8(const float f[8]) {
    __half2 h0 = __floats2half2_rn(f[0], f[1]);
    __half2 h1 = __floats2half2_rn(f[2], f[3]);
    __half2 h2 = __floats2half2_rn(f[4], f[5]);
    __half2 h3 = __floats2half2_rn(f[6], f[7]);
    uint4 raw;
    __builtin_memcpy(&raw.x, &h0, 4);
    __builtin_memcpy(&raw.y, &h1, 4);
    __builtin_memcpy(&raw.z, &h2, 4);
    __builtin_memcpy(&raw.w, &h3, 4);
    return raw;
}

// ---------------- CSR build ----------------

__global__ __launch_bounds__(256) void k_zero_cnt() {
    int i = blockIdx.x * 256 + threadIdx.x;
    if (i < N_NODES) g_rowcnt[i] = 0;
}

__global__ __launch_bounds__(256) void k_hist(const int* __restrict__ dst) {
    int e = blockIdx.x * 256 + threadIdx.x;
    if (e < N_EDGES) atomicAdd(&g_rowcnt[dst[e]], 1);
}

__global__ __launch_bounds__(256) void k_dinv() {
    int i = blockIdx.x * 256 + threadIdx.x;
    if (i < N_NODES) g_dinv[i] = rsqrtf((float)(1 + g_rowcnt[i]));
}

__global__ __launch_bounds__(256) void k_scan1() {
    __shared__ int sh[256];
    int i = blockIdx.x * 256 + threadIdx.x;
    int v = (i < N_NODES) ? g_rowcnt[i] : 0;
    sh[threadIdx.x] = v;
    __syncthreads();
#pragma unroll
    for (int off = 1; off < 256; off <<= 1) {
        int t = (threadIdx.x >= off) ? sh[threadIdx.x - off] : 0;
        __syncthreads();
        sh[threadIdx.x] += t;
        __syncthreads();
    }
    int incl = sh[threadIdx.x];
    if (i < N_NODES) g_row_start[i] = incl - v;
    if (threadIdx.x == 255) g_part[blockIdx.x] = incl;
}

__global__ __launch_bounds__(256) void k_scan2() {
    __shared__ int sh[256];
    int base = threadIdx.x * 16;
    int local[16];
    int s = 0;
#pragma unroll
    for (int k = 0; k < 16; ++k) {
        local[k] = (base + k < NBLK1) ? g_part[base + k] : 0;
        s += local[k];
    }
    sh[threadIdx.x] = s;
    __syncthreads();
#pragma unroll
    for (int off = 1; off < 256; off <<= 1) {
        int t = (threadIdx.x >= off) ? sh[threadIdx.x - off] : 0;
        __syncthreads();
        sh[threadIdx.x] += t;
        __syncthreads();
    }
    int carry = sh[threadIdx.x] - s;
#pragma unroll
    for (int k = 0; k < 16; ++k) {
        if (base + k < NBLK1) {
            int t = local[k];
            g_part[base + k] = carry;
            carry += t;
        }
    }
}

__global__ __launch_bounds__(256) void k_scan3() {
    int i = blockIdx.x * 256 + threadIdx.x;
    if (i < N_NODES) {
        g_row_start[i] += g_part[blockIdx.x];
        g_rowcnt[i] = 0;
    }
    if (i == 0) g_row_start[N_NODES] = N_EDGES;
}

__global__ __launch_bounds__(256) void k_scatter(const int* __restrict__ src,
                                                 const int* __restrict__ dst) {
    int e = blockIdx.x * 256 + threadIdx.x;
    if (e >= N_EDGES) return;
    int d = dst[e];
    int pos = g_row_start[d] + atomicAdd(&g_rowcnt[d], 1);
    g_csr_src[pos] = src[e];
}

// ---------------- W transpose to fp16 (per layer) ----------------
// Wt[n][k] = (fp16) W[k][n]; coalesced read, scattered 2B write (32 KB total).

template <int SEL>
__global__ __launch_bounds__(256) void k_wt(const float* __restrict__ W) {
    __half* dst = (SEL == 0) ? g_wt2 : g_wt3;
    int t = blockIdx.x * 256 + threadIdx.x;   // 0..16383
    int n = t & 127, k = t >> 7;
    dst[n * 128 + k] = __float2half_rn(W[k * 128 + n]);
}

// ---------------- layer 1 ----------------

// px[i] = dinv[i]*x[i]  (px aliases g_hB as f32; dead once layer 2 runs)
__global__ __launch_bounds__(256) void k_p7(const float* __restrict__ x) {
    int i = blockIdx.x * 256 + threadIdx.x;
    if (i >= N_NODES) return;
    float w = g_dinv[i];
    float* px = (float*)g_hB;
#pragma unroll
    for (int k = 0; k < 7; ++k) px[i * 7 + k] = x[i * 7 + k] * w;
}

// agg7[d] = px[d] + sum px[s], 8 lanes/node, 4-deep MLP
__global__ __launch_bounds__(256) void k_agg7_csr() {
    int t = blockIdx.x * 256 + threadIdx.x;
    int i = t >> 3;
    int c = t & 7;
    if (i >= N_NODES || c >= 7) return;
    const float* px = (const float*)g_hB;
    float acc = px[i * 7 + c];
    int e = g_row_start[i], e1 = g_row_start[i + 1];
    for (; e + 4 <= e1; e += 4) {
        int s0 = g_csr_src[e + 0], s1 = g_csr_src[e + 1];
        int s2 = g_csr_src[e + 2], s3 = g_csr_src[e + 3];
        float v0 = px[s0 * 7 + c], v1 = px[s1 * 7 + c];
        float v2 = px[s2 * 7 + c], v3 = px[s3 * 7 + c];
        acc += (v0 + v1) + (v2 + v3);
    }
    for (; e < e1; ++e) acc += px[g_csr_src[e] * 7 + c];
    g_agg7[i * 7 + c] = acc;
}

// h1 = relu(bn(dinv*(agg7.W1) + b)); store q1 = dinv*h1 (fp16, half2 stores)
__global__ __launch_bounds__(256) void k_lin1_bn_relu(const float* __restrict__ W,
                                                      const float* __restrict__ b,
                                                      const float* __restrict__ g,
                                                      const float* __restrict__ bt,
                                                      const float* __restrict__ rm,
                                                      const float* __restrict__ rv) {
    int t = blockIdx.x * 256 + threadIdx.x;   // node*64 + cpair
    int i = t >> 6, c = (t & 63) * 2;
    if (i >= N_NODES) return;
    float a[7];
#pragma unroll
    for (int k = 0; k < 7; ++k) a[k] = g_agg7[i * 7 + k];
    float z0 = 0.f, z1 = 0.f;
#pragma unroll
    for (int k = 0; k < 7; ++k) {
        z0 = fmaf(a[k], W[k * 128 + c], z0);
        z1 = fmaf(a[k], W[k * 128 + c + 1], z1);
    }
    float dv = g_dinv[i];
    z0 *= dv; z1 *= dv;
    float s0 = g[c] * rsqrtf(rv[c] + BN_EPS);
    float s1 = g[c + 1] * rsqrtf(rv[c + 1] + BN_EPS);
    float o0 = fmaf(b[c] - rm[c], s0, bt[c]);
    float o1 = fmaf(b[c + 1] - rm[c + 1], s1, bt[c + 1]);
    float h0 = fmaxf(fmaf(z0, s0, o0), 0.f) * dv;
    float h1 = fmaxf(fmaf(z1, s1, o1), 0.f) * dv;
    __half2 out = __floats2half2_rn(h0, h1);
    *(__half2*)(g_hA + (size_t)i * 128 + c) = out;
}

// ---------------- fused CSR-gather + MFMA GEMM + BN + ReLU ------------------
// 64 nodes/block, 256 threads (4 waves).
// Gather: 16 lanes/node x 8ch (16B fp16 loads), MLP-4, f32 acc -> fp16 As.
// GEMM: v_mfma_f32_16x16x32_f16. Per wave: 16 rows x 128 cols = 8 n-tiles,
//   K=128 in 4 chunks of 32. A-frag: m=lane&15, k=(lane>>4)*8+j (16B LDS read
//   from As, pad 152 -> 2-way banks). B-frag: n=lane&15, same k window, read
//   from Wt chunk staged in LDS (Wtc[128][40], 2-way banks).
// C layout (HW-verified): col=lane&15, row=(lane>>4)*4+reg. Epilogue BN/ReLU,
// C staged through As for coalesced 16B global stores.
// LDS = 64*152*2 + 128*40*2 = 29,696 B -> 5 blocks/CU.
// ROUND-12 FIX: final store loop is 4 iterations (1024 uint4 = 64 rows x 128
// cols). 8 iterations addressed rows 64..127: OOB-LDS garbage raced into the
// NEXT block's output rows -> NaN.

template <bool PRE, bool ATOB, int WSEL>
__global__ __launch_bounds__(256) void k_agg_gemm(const float* __restrict__ b,
                                                  const float* __restrict__ g,
                                                  const float* __restrict__ bt,
                                                  const float* __restrict__ rm,
                                                  const float* __restrict__ rv) {
    const __half* __restrict__ hin  = ATOB ? g_hA : g_hB;
    __half* __restrict__       hout = ATOB ? g_hB : g_hA;
    const __half* __restrict__ WtG  = (WSEL == 0) ? g_wt2 : g_wt3;

    __shared__ __half As[64][152];
    __shared__ __half Wtc[128][40];
    const int tid = threadIdx.x;
    const int node0 = blockIdx.x * 64;

    // ---- gather phase ----
    {
        const int slot = tid >> 4;          // 0..15
        const int c0 = (tid & 15) * 8;      // channel group (8 halfs = 16 B)
#pragma unroll
        for (int pass = 0; pass < 4; ++pass) {
            int i = node0 + pass * 16 + slot;
            float f[8];
            set8(*(const uint4*)(hin + (size_t)i * 128 + c0), f);   // self term
            int e = g_row_start[i], e1 = g_row_start[i + 1];
            for (; e + 4 <= e1; e += 4) {
                int s0 = g_csr_src[e + 0], s1 = g_csr_src[e + 1];
                int s2 = g_csr_src[e + 2], s3 = g_csr_src[e + 3];
                uint4 r0 = *(const uint4*)(hin + (size_t)s0 * 128 + c0);
                uint4 r1 = *(const uint4*)(hin + (size_t)s1 * 128 + c0);
                uint4 r2 = *(const uint4*)(hin + (size_t)s2 * 128 + c0);
                uint4 r3 = *(const uint4*)(hin + (size_t)s3 * 128 + c0);
                add8(r0, f); add8(r1, f); add8(r2, f); add8(r3, f);
            }
            for (; e < e1; ++e) {
                int s = g_csr_src[e];
                add8(*(const uint4*)(hin + (size_t)s * 128 + c0), f);
            }
            int row = pass * 16 + slot;
            *(uint4*)(&As[row][c0]) = pack8(f);
        }
    }

    // ---- MFMA GEMM phase ----
    const int wv = tid >> 6;        // wave 0..3
    const int lane = tid & 63;
    const int lm = lane & 15;       // m (a-frag) / n (b-frag) / col (c-frag)
    const int lq = lane >> 4;       // quad
    const int m0 = wv * 16;

    f32x4 acc[8];
#pragma unroll
    for (int nt = 0; nt < 8; ++nt) acc[nt] = (f32x4){0.f, 0.f, 0.f, 0.f};

    for (int kb = 0; kb < 4; ++kb) {
        __syncthreads();               // kb=0: gather visible; else: Wtc reads done
#pragma unroll
        for (int i2 = 0; i2 < 2; ++i2) {
            int u = tid + i2 * 256;    // 0..511
            int n = u >> 2, kq = (u & 3) << 3;
            *(uint4*)(&Wtc[n][kq]) = *(const uint4*)(WtG + n * 128 + kb * 32 + kq);
        }
        __syncthreads();
        f16x8 afr;
        __builtin_memcpy(&afr, &As[m0 + lm][kb * 32 + lq * 8], 16);
#pragma unroll
        for (int nt = 0; nt < 8; ++nt) {
            f16x8 bfr;
            __builtin_memcpy(&bfr, &Wtc[nt * 16 + lm][lq * 8], 16);
            acc[nt] = __builtin_amdgcn_mfma_f32_16x16x32_f16(afr, bfr, acc[nt], 0, 0, 0);
        }
    }

    // ---- epilogue: BN/ReLU, stage C in As (fp16), coalesced store ----
    float4 dv4 = *(const float4*)(g_dinv + node0 + m0 + lq * 4);
    float dvr[4] = {dv4.x, dv4.y, dv4.z, dv4.w};

    __syncthreads();   // all MFMA reads of As done before overwrite
#pragma unroll
    for (int nt = 0; nt < 8; ++nt) {
        int c = nt * 16 + lm;
        float s = g[c] * rsqrtf(rv[c] + BN_EPS);
        float o = fmaf(b[c] - rm[c], s, bt[c]);
#pragma unroll
        for (int r = 0; r < 4; ++r) {
            float pm = PRE ? dvr[r] : 1.0f;
            float y = fmaxf(fmaf(acc[nt][r] * dvr[r], s, o), 0.f) * pm;
            As[m0 + lq * 4 + r][c] = __float2half_rn(y);
        }
    }
    __syncthreads();
#pragma unroll
    for (int i = 0; i < 4; ++i) {       // 1024 uint4 = 64 rows x 128 cols (FIX)
        int u = tid + i * 256;          // 0..1023
        int row = u >> 4, cc = (u & 15) << 3;
        *(uint4*)(hout + (size_t)(node0 + row) * 128 + cc) = *(const uint4*)(&As[row][cc]);
    }
}

// ---------------- pooling + head ----------------

__global__ __launch_bounds__(256) void k_gstart(const int* __restrict__ batch) {
    int gidx = blockIdx.x * 256 + threadIdx.x;
    if (gidx > N_GRAPHS) return;
    int lo = 0, hi = N_NODES;
    while (lo < hi) {
        int mid = (lo + hi) >> 1;
        if (batch[mid] < gidx) lo = mid + 1; else hi = mid;
    }
    g_gstart[gidx] = lo;
}

__global__ __launch_bounds__(256) void k_pool_seg() {
    int t = blockIdx.x * 256 + threadIdx.x;
    int gi = t >> 4;
    if (gi >= N_GRAPHS) return;
    int c0 = (t & 15) * 8;
    int s0 = g_gstart[gi], s1 = g_gstart[gi + 1];
    float f[8] = {0.f, 0.f, 0.f, 0.f, 0.f, 0.f, 0.f, 0.f};
    for (int i = s0; i < s1; ++i)
        add8(*(const uint4*)(g_hA + (size_t)i * 128 + c0), f);
    float inv = 1.0f / (float)max(s1 - s0, 1);
    float* pooled = g_agg7;
    *(float4*)(pooled + (size_t)gi * 128 + c0)     = make_float4(f[0]*inv, f[1]*inv, f[2]*inv, f[3]*inv);
    *(float4*)(pooled + (size_t)gi * 128 + c0 + 4) = make_float4(f[4]*inv, f[5]*inv, f[6]*inv, f[7]*inv);
}

__global__ __launch_bounds__(256) void k_head1(const float* __restrict__ Wc1,
                                               const float* __restrict__ bc1) {
    int t = blockIdx.x * 256 + threadIdx.x;
    int gi = t >> 6, c = t & 63;
    if (gi >= N_GRAPHS) return;
    const float* pooled = g_agg7;
    float* hidden = g_agg7 + HIDDEN_OFF;
    float z = 0.f;
#pragma unroll 8
    for (int k = 0; k < 128; ++k) z = fmaf(pooled[gi * 128 + k], Wc1[k * 64 + c], z);
    hidden[t] = fmaxf(z + bc1[c], 0.f);
}

__global__ __launch_bounds__(256) void k_head2(const float* __restrict__ Wc2,
                                               const float* __restrict__ bc2,
                                               float* __restrict__ out) {
    int gi = blockIdx.x * 256 + threadIdx.x;
    if (gi >= N_GRAPHS) return;
    const float* hidden = g_agg7 + HIDDEN_OFF;
    float z = bc2[0];
#pragma unroll 8
    for (int k = 0; k < 64; ++k) z = fmaf(hidden[gi * 64 + k], Wc2[k], z);
    out[gi] = z;
}

// ---------------- launch ----------------

extern "C" void kernel_launch(void* const* d_in, const int* in_sizes, int n_in,
                              void* d_out, int out_size, void* d_ws, size_t ws_size,
                              hipStream_t stream) {
    const float* x     = (const float*)d_in[0];
    const int*   ei    = (const int*)d_in[1];
    const int*   batch = (const int*)d_in[2];
    const float* W1 = (const float*)d_in[3];
    const float* b1 = (const float*)d_in[4];
    const float* g1 = (const float*)d_in[5];
    const float* bt1= (const float*)d_in[6];
    const float* rm1= (const float*)d_in[7];
    const float* rv1= (const float*)d_in[8];
    const float* W2 = (const float*)d_in[9];
    const float* b2 = (const float*)d_in[10];
    const float* g2 = (const float*)d_in[11];
    const float* bt2= (const float*)d_in[12];
    const float* rm2= (const float*)d_in[13];
    const float* rv2= (const float*)d_in[14];
    const float* W3 = (const float*)d_in[15];
    const float* b3 = (const float*)d_in[16];
    const float* g3 = (const float*)d_in[17];
    const float* bt3= (const float*)d_in[18];
    const float* rm3= (const float*)d_in[19];
    const float* rv3= (const float*)d_in[20];
    const float* Wc1= (const float*)d_in[21];
    const float* bc1= (const float*)d_in[22];
    const float* Wc2= (const float*)d_in[23];
    const float* bc2= (const float*)d_in[24];
    float* outp = (float*)d_out;
    (void)d_ws; (void)ws_size; (void)n_in; (void)in_sizes;

    const int* srcp = ei;
    const int* dstp = ei + N_EDGES;

    // CSR build (by dst) + dinv
    k_zero_cnt<<<NBLK1, 256, 0, stream>>>();
    k_hist<<<(N_EDGES + 255) / 256, 256, 0, stream>>>(dstp);
    k_dinv<<<NBLK1, 256, 0, stream>>>();
    k_scan1<<<NBLK1, 256, 0, stream>>>();
    k_scan2<<<1, 256, 0, stream>>>();
    k_scan3<<<NBLK1, 256, 0, stream>>>();
    k_scatter<<<(N_EDGES + 255) / 256, 256, 0, stream>>>(srcp, dstp);

    // W2/W3 -> fp16 transposed (for MFMA B-fragments)
    k_wt<0><<<64, 256, 0, stream>>>(W2);
    k_wt<1><<<64, 256, 0, stream>>>(W3);

    // graph boundaries for pooling
    k_gstart<<<(N_GRAPHS + 1 + 255) / 256, 256, 0, stream>>>(batch);

    // layer 1: premultiply -> gather -> linear+BN+ReLU
    k_p7<<<(N_NODES + 255) / 256, 256, 0, stream>>>(x);
    k_agg7_csr<<<(N_NODES * 8) / 256, 256, 0, stream>>>();
    k_lin1_bn_relu<<<(N_NODES * 64) / 256, 256, 0, stream>>>(W1, b1, g1, bt1, rm1, rv1);

    // layers 2,3: fused gather + MFMA GEMM, ping-pong hA <-> hB
    k_agg_gemm<true,  true,  0><<<N_NODES / 64, 256, 0, stream>>>(b2, g2, bt2, rm2, rv2);
    k_agg_gemm<false, false, 1><<<N_NODES / 64, 256, 0, stream>>>(b3, g3, bt3, rm3, rv3);

    // segment-mean pool + head MLP
    k_pool_seg<<<(N_GRAPHS * 16) / 256, 256, 0, stream>>>();
    k_head1<<<(N_GRAPHS * 64) / 256, 256, 0, stream>>>(Wc1, bc1);
    k_head2<<<(N_GRAPHS + 255) / 256, 256, 0, stream>>>(Wc2, bc2, outp);
}